// Round 8
// baseline (1184.308 us; speedup 1.0000x reference)
//
#include <hip/hip_runtime.h>
#include <hip/hip_bf16.h>

#define N_NODES 100000
#define N_EDGES 3200000
#define N_GRAPHS 128
#define FIN 512
#define NCLS 128
#define HID 256
#define OUT_DIM 10
#define BN_EPS 1e-5f

#define NBUCK 391                      // ceil(N_NODES/256): bucket = dst >> 8
#define EPB   ((N_EDGES + NBUCK - 1) / NBUCK)   // edges per partition block
#define STATS_CPY 1536                 // 3 layers * 2 * HID, per-XCD copy stride
#define AGG_BLOCKS 2048                // persistent grid for aggregation

typedef unsigned short ush;
typedef ush su16x8 __attribute__((ext_vector_type(8)));
typedef ush su16x4 __attribute__((ext_vector_type(4)));
typedef __bf16 bf16x8v __attribute__((ext_vector_type(8)));
typedef float f32x4v __attribute__((ext_vector_type(4)));

__device__ __forceinline__ float bf2f(ush u) {
    union { unsigned int i; float f; } v; v.i = ((unsigned int)u) << 16; return v.f;
}
// native conversion: compiler emits v_cvt_pk_bf16_f32 for pairs (RNE)
__device__ __forceinline__ ush f2bf(float f) {
    __hip_bfloat16 b = __float2bfloat16(f);
    return __builtin_bit_cast(ush, b);
}

// MFMA shim: works whether the gfx950 builtin takes 16-bit-int vectors or __bf16 vectors.
template <typename T>
__device__ __forceinline__ auto mfma_sel(T a, T b, f32x4v c, int)
    -> decltype(__builtin_amdgcn_mfma_f32_16x16x32_bf16(a, b, c, 0, 0, 0)) {
    return __builtin_amdgcn_mfma_f32_16x16x32_bf16(a, b, c, 0, 0, 0);
}
template <typename T>
__device__ __forceinline__ f32x4v mfma_sel(T a, T b, f32x4v c, long) {
    return __builtin_amdgcn_mfma_f32_16x16x32_bf16(
        __builtin_bit_cast(bf16x8v, a), __builtin_bit_cast(bf16x8v, b), c, 0, 0, 0);
}
__device__ __forceinline__ f32x4v MFMA_BF16(su16x8 a, su16x8 b, f32x4v c) {
    return mfma_sel(a, b, c, 0);
}

// ---------------- zero pass (replaces 3 memsets) ----------------
__global__ void zero_kernel(int* __restrict__ odeg8, int* __restrict__ bcnt,
                            float* __restrict__ stats8, float* __restrict__ hg) {
    int i = blockIdx.x * 256 + threadIdx.x;
    if (i < 8 * N_NODES) odeg8[i] = 0;
    if (i <= NBUCK) bcnt[i] = 0;
    if (i < 8 * STATS_CPY) stats8[i] = 0.f;
    if (i < N_GRAPHS * HID) hg[i] = 0.f;
}

// ---------------- edge pass 1: out-degree (8 XCD-local copies) + bucket histogram + bcnt ----------------
__global__ __launch_bounds__(256) void edge_pass1(const int* __restrict__ src,
                                                  const int* __restrict__ dst,
                                                  int* __restrict__ odeg8,
                                                  int* __restrict__ hist,
                                                  int* __restrict__ bcnt) {
    __shared__ int hc[NBUCK];
    int tid = threadIdx.x, blk = blockIdx.x;
    for (int i = tid; i < NBUCK; i += 256) hc[i] = 0;
    __syncthreads();
    int e0 = blk * EPB, e1 = e0 + EPB; if (e1 > N_EDGES) e1 = N_EDGES;
    int c = blk & 7;
    for (int e = e0 + tid; e < e1; e += 256) {
        atomicAdd(&odeg8[(size_t)c * N_NODES + src[e]], 1);
        atomicAdd(&hc[dst[e] >> 8], 1);
    }
    __syncthreads();
    for (int i = tid; i < NBUCK; i += 256) {
        int v = hc[i];
        hist[(size_t)blk * NBUCK + i] = v;
        if (v) atomicAdd(&bcnt[i], v);
    }
}

// ---------------- merged prep: nsrc + gstart + weight conversion ----------------
#define CVT_TOTAL (NCLS * FIN + HID * NCLS + HID * HID + HID * HID)
__global__ void misc_prep(const int* __restrict__ odeg8, float* __restrict__ nsrc,
                          const int* __restrict__ gids, int* __restrict__ gstart,
                          const float* __restrict__ w0, const float* __restrict__ l0,
                          const float* __restrict__ l1, const float* __restrict__ l2,
                          ush* __restrict__ wB0, ush* __restrict__ t0,
                          ush* __restrict__ t1, ush* __restrict__ t2) {
    int i = blockIdx.x * 256 + threadIdx.x;
    if (i < N_NODES) {
        int od = 0;
        #pragma unroll
        for (int c = 0; c < 8; c++) od += odeg8[(size_t)c * N_NODES + i];
        nsrc[i] = od > 0 ? rsqrtf((float)od) : 0.f;
        int g = gids[i];
        int gp = (i == 0) ? -1 : gids[i - 1];
        for (int gg = gp + 1; gg <= g; gg++) gstart[gg] = i;
        if (i == N_NODES - 1) {
            for (int gg = g + 1; gg <= N_GRAPHS; gg++) gstart[gg] = N_NODES;
        }
        return;
    }
    i -= N_NODES;
    if (i < NCLS * FIN) { wB0[i] = f2bf(w0[i]); return; }
    i -= NCLS * FIN;
    if (i < HID * NCLS) { int n = i >> 7, k = i & 127; t0[i] = f2bf(l0[k * HID + n]); return; }
    i -= HID * NCLS;
    if (i < HID * HID) { int n = i >> 8, k = i & 255; t1[i] = f2bf(l1[k * HID + n]); return; }
    i -= HID * HID;
    if (i < HID * HID) { int n = i >> 8, k = i & 255; t2[i] = f2bf(l2[k * HID + n]); }
}

// ---------------- pass Bscan — exclusive scan of bucket totals ----------------
__global__ __launch_bounds__(512) void bscan_kernel(const int* __restrict__ bcnt,
                                                    int* __restrict__ bbase) {
    __shared__ int a[512];
    int tid = threadIdx.x;
    int v = (tid < NBUCK) ? bcnt[tid] : 0;
    a[tid] = v;
    __syncthreads();
    for (int s = 1; s < 512; s <<= 1) {
        int y = (tid >= s) ? a[tid - s] : 0;
        __syncthreads();
        a[tid] += y;
        __syncthreads();
    }
    if (tid < NBUCK) bbase[tid] = a[tid] - v;
    if (tid == 0) bbase[NBUCK] = N_EDGES;
}

// ---------------- pass B2 — per-(block,bucket) offsets ----------------
__global__ __launch_bounds__(512) void boff_kernel(const int* __restrict__ hist,
                                                   const int* __restrict__ bbase,
                                                   int* __restrict__ off) {
    __shared__ int a[512];
    int b = blockIdx.x, tid = threadIdx.x;
    int v = (tid < NBUCK) ? hist[(size_t)tid * NBUCK + b] : 0;
    a[tid] = v;
    __syncthreads();
    for (int s = 1; s < 512; s <<= 1) {
        int y = (tid >= s) ? a[tid - s] : 0;
        __syncthreads();
        a[tid] += y;
        __syncthreads();
    }
    if (tid < NBUCK) off[(size_t)tid * NBUCK + b] = bbase[b] + a[tid] - v;
}

// ---------------- pass C — stage edges into bucket-contiguous runs ----------------
__global__ __launch_bounds__(256) void stage_kernel(const int* __restrict__ src,
                                                    const int* __restrict__ dst,
                                                    const int* __restrict__ off,
                                                    unsigned int* __restrict__ staged) {
    __shared__ int cur[NBUCK];
    int tid = threadIdx.x, blk = blockIdx.x;
    for (int i = tid; i < NBUCK; i += 256) cur[i] = off[(size_t)blk * NBUCK + i];
    __syncthreads();
    int e0 = blk * EPB, e1 = e0 + EPB; if (e1 > N_EDGES) e1 = N_EDGES;
    for (int e = e0 + tid; e < e1; e += 256) {
        int d = dst[e], s = src[e];
        int pos = atomicAdd(&cur[d >> 8], 1);
        staged[pos] = ((unsigned int)(d & 255) << 24) | (unsigned int)s;
    }
}

// ---------------- pass D — exact CSR within bucket + roff + ndst ----------------
__global__ __launch_bounds__(256) void csr_kernel(const unsigned int* __restrict__ staged,
                                                  const int* __restrict__ bbase,
                                                  int* __restrict__ roff,
                                                  float* __restrict__ ndst,
                                                  int* __restrict__ csr) {
    __shared__ int cnt[256], pfx[256], cur[256];
    int b = blockIdx.x, tid = threadIdx.x;
    int beg = bbase[b], end = bbase[b + 1];
    int nodeBase = b * 256;
    int nNodes = N_NODES - nodeBase; if (nNodes > 256) nNodes = 256;
    cnt[tid] = 0;
    __syncthreads();
    for (int e = beg + tid; e < end; e += 256) atomicAdd(&cnt[staged[e] >> 24], 1);
    __syncthreads();
    int v = cnt[tid];
    pfx[tid] = v;
    __syncthreads();
    for (int s = 1; s < 256; s <<= 1) {
        int y = (tid >= s) ? pfx[tid - s] : 0;
        __syncthreads();
        pfx[tid] += y;
        __syncthreads();
    }
    int excl = pfx[tid] - v;
    pfx[tid] = excl;
    cur[tid] = 0;
    if (tid < nNodes) {
        int node = nodeBase + tid;
        roff[node] = beg + excl;
        ndst[node] = v > 0 ? rsqrtf((float)v) : 0.f;
    }
    if (b == NBUCK - 1 && tid == 0) roff[N_NODES] = N_EDGES;
    __syncthreads();
    for (int e = beg + tid; e < end; e += 256) {
        unsigned int w = staged[e];
        int dl = w >> 24;
        int pos = beg + pfx[dl] + atomicAdd(&cur[dl], 1);
        csr[pos] = (int)(w & 0xFFFFFFu);
    }
}

// ---------------- MFMA GEMM: C[M,NN](bf16) = A[M,K] @ BT[NN,K]^T ----------------
// stats (if enabled) go to per-XCD copy: stats + ((linear block id)&7)*STATS_CPY
template <bool A_F32, bool DO_STATS>
__global__ __launch_bounds__(256) void mfma_gemm(
    const void* __restrict__ Aptr, const ush* __restrict__ BT,
    ush* __restrict__ C, int M, int K, int NN,
    const float* __restrict__ rowscale, const float* __restrict__ bias,
    float* __restrict__ stats)
{
    __shared__ __align__(16) ush As[128][40];
    __shared__ __align__(16) ush Bs[128][40];
    const int bn0 = blockIdx.x * 128;
    const int bm0 = blockIdx.y * 128;
    const int tid = threadIdx.x;
    const int lane = tid & 63;
    const int wv = tid >> 6;
    const int wm = (wv >> 1) * 64;
    const int wn = (wv & 1) * 64;
    const int lm = lane & 15;
    const int lg = lane >> 4;

    f32x4v zero = {0.f, 0.f, 0.f, 0.f};
    f32x4v acc[4][4];
    #pragma unroll
    for (int mi = 0; mi < 4; mi++)
        #pragma unroll
        for (int ni = 0; ni < 4; ni++) acc[mi][ni] = zero;

    for (int k0 = 0; k0 < K; k0 += 32) {
        #pragma unroll
        for (int i = 0; i < 2; i++) {
            int seg = tid + i * 256;
            int n = seg >> 2, kp = seg & 3;
            su16x8 v = *(const su16x8*)&BT[(size_t)(bn0 + n) * K + k0 + kp * 8];
            *(su16x8*)&Bs[n][kp * 8] = v;
        }
        if constexpr (A_F32) {
            const float* Af = (const float*)Aptr;
            #pragma unroll
            for (int i = 0; i < 4; i++) {
                int seg = tid + i * 256;
                int m = seg >> 3, kp = seg & 7;
                int gm = bm0 + m; if (gm >= M) gm = M - 1;
                float4 v = *(const float4*)&Af[(size_t)gm * K + k0 + kp * 4];
                su16x4 o = { f2bf(v.x), f2bf(v.y), f2bf(v.z), f2bf(v.w) };
                *(su16x4*)&As[m][kp * 4] = o;
            }
        } else {
            const ush* Ab = (const ush*)Aptr;
            #pragma unroll
            for (int i = 0; i < 2; i++) {
                int seg = tid + i * 256;
                int m = seg >> 2, kp = seg & 3;
                int gm = bm0 + m; if (gm >= M) gm = M - 1;
                su16x8 v = *(const su16x8*)&Ab[(size_t)gm * K + k0 + kp * 8];
                *(su16x8*)&As[m][kp * 8] = v;
            }
        }
        __syncthreads();
        su16x8 af[4], bfr[4];
        #pragma unroll
        for (int i = 0; i < 4; i++)
            af[i] = *(const su16x8*)&As[wm + i * 16 + lm][lg * 8];
        #pragma unroll
        for (int i = 0; i < 4; i++)
            bfr[i] = *(const su16x8*)&Bs[wn + i * 16 + lm][lg * 8];
        #pragma unroll
        for (int mi = 0; mi < 4; mi++)
            #pragma unroll
            for (int ni = 0; ni < 4; ni++)
                acc[mi][ni] = MFMA_BF16(af[mi], bfr[ni], acc[mi][ni]);
        __syncthreads();
    }

    float s4[4] = {0.f, 0.f, 0.f, 0.f}, q4[4] = {0.f, 0.f, 0.f, 0.f};
    #pragma unroll
    for (int mi = 0; mi < 4; mi++) {
        #pragma unroll
        for (int j = 0; j < 4; j++) {
            int gm = bm0 + wm + mi * 16 + lg * 4 + j;
            bool valid = gm < M;
            float rs = (rowscale && valid) ? rowscale[gm] : 1.f;
            #pragma unroll
            for (int ni = 0; ni < 4; ni++) {
                int gn = bn0 + wn + ni * 16 + lm;
                float v = acc[mi][ni][j] * rs;
                if (bias) v += bias[gn];
                if (valid) {
                    C[(size_t)gm * NN + gn] = f2bf(v);
                    if constexpr (DO_STATS) { s4[ni] += v; q4[ni] += v * v; }
                }
            }
        }
    }
    if constexpr (DO_STATS) {
        float* st = stats + ((blockIdx.x + gridDim.x * blockIdx.y) & 7) * STATS_CPY;
        #pragma unroll
        for (int ni = 0; ni < 4; ni++) {
            s4[ni] += __shfl_xor(s4[ni], 16); s4[ni] += __shfl_xor(s4[ni], 32);
            q4[ni] += __shfl_xor(q4[ni], 16); q4[ni] += __shfl_xor(q4[ni], 32);
        }
        if (lg == 0) {
            #pragma unroll
            for (int ni = 0; ni < 4; ni++) {
                int gn = bn0 + wn + ni * 16 + lm;
                atomicAdd(&st[gn], s4[ni]);
                atomicAdd(&st[HID + gn], q4[ni]);
            }
        }
    }
}

// ---------------- layer-0 aggregation (D=128): persistent waves, 4 slots, unroll-4 ----------------
__global__ __launch_bounds__(256) void agg128(const ush* __restrict__ hs,
                                              const int* __restrict__ roff,
                                              const int* __restrict__ csr,
                                              ush* __restrict__ out)
{
    const int wgid = (blockIdx.x * 256 + threadIdx.x) >> 6;
    const int W = (AGG_BLOCKS * 256) >> 6;
    const int lane = threadIdx.x & 63;
    const int q = lane >> 4;
    const int c0 = (lane & 15) * 8;
    for (int node = wgid; node < N_NODES; node += W) {
        int beg = roff[node], end = roff[node + 1];
        int len = end - beg;
        int s = beg + ((len * q) >> 2);
        int t = beg + ((len * (q + 1)) >> 2);
        float a0[8] = {}, a1[8] = {}, a2[8] = {}, a3[8] = {};
        int e = s;
        for (; e + 3 < t; e += 4) {
            int i0 = __builtin_nontemporal_load(&csr[e]);
            int i1 = __builtin_nontemporal_load(&csr[e + 1]);
            int i2 = __builtin_nontemporal_load(&csr[e + 2]);
            int i3 = __builtin_nontemporal_load(&csr[e + 3]);
            su16x8 v0 = *(const su16x8*)&hs[(size_t)i0 * 128 + c0];
            su16x8 v1 = *(const su16x8*)&hs[(size_t)i1 * 128 + c0];
            su16x8 v2 = *(const su16x8*)&hs[(size_t)i2 * 128 + c0];
            su16x8 v3 = *(const su16x8*)&hs[(size_t)i3 * 128 + c0];
            #pragma unroll
            for (int j = 0; j < 8; j++) {
                a0[j] += bf2f(v0[j]); a1[j] += bf2f(v1[j]);
                a2[j] += bf2f(v2[j]); a3[j] += bf2f(v3[j]);
            }
        }
        for (; e < t; e++) {
            int i0 = __builtin_nontemporal_load(&csr[e]);
            su16x8 v0 = *(const su16x8*)&hs[(size_t)i0 * 128 + c0];
            #pragma unroll
            for (int j = 0; j < 8; j++) a0[j] += bf2f(v0[j]);
        }
        #pragma unroll
        for (int j = 0; j < 8; j++) {
            a0[j] += a1[j] + a2[j] + a3[j];
            a0[j] += __shfl_xor(a0[j], 16);
            a0[j] += __shfl_xor(a0[j], 32);
        }
        if (lane < 16) {
            su16x8 o;
            #pragma unroll
            for (int j = 0; j < 8; j++) o[j] = f2bf(a0[j]);
            __builtin_nontemporal_store(o, (su16x8*)&out[(size_t)node * 128 + c0]);
        }
    }
}

// ---------------- layers 1,2 aggregation (D=256): persistent waves, 2 slots, unroll-4 ----------------
__global__ __launch_bounds__(256) void agg256(const ush* __restrict__ Q,
                                              const int* __restrict__ roff,
                                              const int* __restrict__ csr,
                                              ush* __restrict__ out)
{
    const int wgid = (blockIdx.x * 256 + threadIdx.x) >> 6;
    const int W = (AGG_BLOCKS * 256) >> 6;
    const int lane = threadIdx.x & 63;
    const int half = lane >> 5;
    const int c0 = (lane & 31) * 8;
    for (int node = wgid; node < N_NODES; node += W) {
        int beg = roff[node], end = roff[node + 1];
        int len = end - beg;
        int s = beg + ((len * half) >> 1);
        int t = beg + ((len * (half + 1)) >> 1);
        float a0[8] = {}, a1[8] = {}, a2[8] = {}, a3[8] = {};
        int e = s;
        for (; e + 3 < t; e += 4) {
            int i0 = __builtin_nontemporal_load(&csr[e]);
            int i1 = __builtin_nontemporal_load(&csr[e + 1]);
            int i2 = __builtin_nontemporal_load(&csr[e + 2]);
            int i3 = __builtin_nontemporal_load(&csr[e + 3]);
            su16x8 v0 = *(const su16x8*)&Q[(size_t)i0 * 256 + c0];
            su16x8 v1 = *(const su16x8*)&Q[(size_t)i1 * 256 + c0];
            su16x8 v2 = *(const su16x8*)&Q[(size_t)i2 * 256 + c0];
            su16x8 v3 = *(const su16x8*)&Q[(size_t)i3 * 256 + c0];
            #pragma unroll
            for (int j = 0; j < 8; j++) {
                a0[j] += bf2f(v0[j]); a1[j] += bf2f(v1[j]);
                a2[j] += bf2f(v2[j]); a3[j] += bf2f(v3[j]);
            }
        }
        for (; e < t; e++) {
            int i0 = __builtin_nontemporal_load(&csr[e]);
            su16x8 v0 = *(const su16x8*)&Q[(size_t)i0 * 256 + c0];
            #pragma unroll
            for (int j = 0; j < 8; j++) a0[j] += bf2f(v0[j]);
        }
        #pragma unroll
        for (int j = 0; j < 8; j++) {
            a0[j] += a1[j] + a2[j] + a3[j];
            a0[j] += __shfl_xor(a0[j], 32);
        }
        if (lane < 32) {
            su16x8 o;
            #pragma unroll
            for (int j = 0; j < 8; j++) o[j] = f2bf(a0[j]);
            __builtin_nontemporal_store(o, (su16x8*)&out[(size_t)node * 256 + c0]);
        }
    }
}

// ---------------- BN apply pass: Q = relu(BN(P)) * nsrc (sums 8 stats copies) ----------------
__global__ __launch_bounds__(256) void bnq_kernel(const ush* __restrict__ P,
                                                  const float* __restrict__ stats,
                                                  const float* __restrict__ gamma,
                                                  const float* __restrict__ beta,
                                                  const float* __restrict__ nsrc,
                                                  ush* __restrict__ Q)
{
    __shared__ float sa[HID], sb[HID];
    int tid = threadIdx.x;
    {
        float ssum = 0.f, qsum = 0.f;
        #pragma unroll
        for (int c8 = 0; c8 < 8; c8++) {
            ssum += stats[c8 * STATS_CPY + tid];
            qsum += stats[c8 * STATS_CPY + HID + tid];
        }
        const float inv_n = 1.f / (float)N_NODES;
        float mu = ssum * inv_n;
        float var = fmaf(-mu, mu, qsum * inv_n);
        float a = gamma[tid] * rsqrtf(var + BN_EPS);
        sa[tid] = a;
        sb[tid] = fmaf(-mu, a, beta[tid]);
    }
    __syncthreads();
    const int total = N_NODES * 32;
    for (int idx = blockIdx.x * 256 + tid; idx < total; idx += gridDim.x * 256) {
        int r = idx >> 5, c0 = (idx & 31) * 8;
        su16x8 v = __builtin_nontemporal_load((const su16x8*)&P[(size_t)r * HID + c0]);
        float ns = nsrc[r];
        su16x8 o;
        #pragma unroll
        for (int j = 0; j < 8; j++) {
            float x = fmaxf(fmaf(bf2f(v[j]), sa[c0 + j], sb[c0 + j]), 0.f) * ns;
            o[j] = f2bf(x);
        }
        *(su16x8*)&Q[(size_t)r * HID + c0] = o;
    }
}

// ---------------- per-graph max with fused BN+ReLU (hg pre-zeroed) ----------------
__global__ __launch_bounds__(256) void segmax_ab(const ush* __restrict__ pre,
                                                 const float* __restrict__ stats,
                                                 const float* __restrict__ gamma,
                                                 const float* __restrict__ beta,
                                                 const int* __restrict__ gstart,
                                                 float* __restrict__ hg) {
    int c = threadIdx.x;
    float ssum = 0.f, qsum = 0.f;
    #pragma unroll
    for (int c8 = 0; c8 < 8; c8++) {
        ssum += stats[c8 * STATS_CPY + c];
        qsum += stats[c8 * STATS_CPY + HID + c];
    }
    const float inv_n = 1.f / (float)N_NODES;
    float mu = ssum * inv_n;
    float var = fmaf(-mu, mu, qsum * inv_n);
    float a = gamma[c] * rsqrtf(var + BN_EPS);
    float b = fmaf(-mu, a, beta[c]);
    int g = blockIdx.x;
    int chunk = blockIdx.y;
    int beg = gstart[g], end = gstart[g + 1];
    int len = end - beg;
    int per = (len + 7) >> 3;
    int s = beg + chunk * per;
    int e = s + per; if (e > end) e = end;
    float m0 = 0.f, m1 = 0.f;
    int n = s;
    for (; n + 1 < e; n += 2) {
        m0 = fmaxf(m0, fmaf(bf2f(pre[(size_t)n * HID + c]), a, b));
        m1 = fmaxf(m1, fmaf(bf2f(pre[(size_t)(n + 1) * HID + c]), a, b));
    }
    if (n < e) m0 = fmaxf(m0, fmaf(bf2f(pre[(size_t)n * HID + c]), a, b));
    float m = fmaxf(fmaxf(m0, m1), 0.f);
    atomicMax((int*)&hg[g * HID + c], __float_as_int(m));
}

// ---------------- final fc ----------------
__global__ void fc_kernel(const float* __restrict__ hg, const float* __restrict__ w,
                          const float* __restrict__ b, float* __restrict__ out) {
    int idx = blockIdx.x * 256 + threadIdx.x;
    if (idx >= N_GRAPHS * OUT_DIM) return;
    int g = idx / OUT_DIM, j = idx % OUT_DIM;
    float s = b[j];
    for (int c = 0; c < HID; c++) s += hg[g * HID + c] * w[c * OUT_DIM + j];
    out[idx] = s;
}

extern "C" void kernel_launch(void* const* d_in, const int* in_sizes, int n_in,
                              void* d_out, int out_size, void* d_ws, size_t ws_size,
                              hipStream_t stream) {
    const float* h      = (const float*)d_in[0];
    const int*   src    = (const int*)d_in[1];
    const int*   dst    = (const int*)d_in[2];
    const int*   gids   = (const int*)d_in[3];
    const float* w_init = (const float*)d_in[4];
    const float* lw[3]    = { (const float*)d_in[5],  (const float*)d_in[9],  (const float*)d_in[13] };
    const float* lb[3]    = { (const float*)d_in[6],  (const float*)d_in[10], (const float*)d_in[14] };
    const float* gamma[3] = { (const float*)d_in[7],  (const float*)d_in[11], (const float*)d_in[15] };
    const float* beta[3]  = { (const float*)d_in[8],  (const float*)d_in[12], (const float*)d_in[16] };
    const float* fc_w = (const float*)d_in[17];
    const float* fc_b = (const float*)d_in[18];
    float* out = (float*)d_out;

    // ---- workspace layout ----
    char* ws = (char*)d_ws;
    size_t off_b = 0;
    auto alloc = [&](size_t bytes) { size_t o = off_b; off_b += (bytes + 255) & ~(size_t)255; return o; };
    size_t o_h0s   = alloc((size_t)N_NODES * NCLS * 2);
    size_t o_aggb  = alloc((size_t)N_NODES * HID * 2);
    size_t o_P     = alloc((size_t)N_NODES * HID * 2);
    size_t o_Q     = alloc((size_t)N_NODES * HID * 2);
    size_t o_wB0   = alloc((size_t)NCLS * FIN * 2);
    size_t o_lwT0  = alloc((size_t)HID * NCLS * 2);
    size_t o_lwT1  = alloc((size_t)HID * HID * 2);
    size_t o_lwT2  = alloc((size_t)HID * HID * 2);
    size_t o_nsrc  = alloc((size_t)N_NODES * 4);
    size_t o_ndst  = alloc((size_t)N_NODES * 4);
    size_t o_odeg8 = alloc((size_t)8 * N_NODES * 4);
    size_t o_roff  = alloc((size_t)(N_NODES + 1) * 4);
    size_t o_csr   = alloc((size_t)N_EDGES * 4);
    size_t o_stg   = alloc((size_t)N_EDGES * 4);
    size_t o_hist  = alloc((size_t)NBUCK * NBUCK * 4);
    size_t o_off   = alloc((size_t)NBUCK * NBUCK * 4);
    size_t o_bcnt  = alloc((size_t)(NBUCK + 1) * 4);
    size_t o_bbase = alloc((size_t)(NBUCK + 1) * 4);
    size_t o_stat8 = alloc((size_t)8 * STATS_CPY * 4);
    size_t o_gst   = alloc((size_t)(N_GRAPHS + 1) * 4);
    size_t o_hg    = alloc((size_t)N_GRAPHS * HID * 4);
    if (off_b > ws_size) return;

    ush*   h0s  = (ush*)(ws + o_h0s);
    ush*   aggb = (ush*)(ws + o_aggb);
    ush*   P    = (ush*)(ws + o_P);
    ush*   Q    = (ush*)(ws + o_Q);
    ush*   wB0  = (ush*)(ws + o_wB0);
    ush*   lwT[3] = { (ush*)(ws + o_lwT0), (ush*)(ws + o_lwT1), (ush*)(ws + o_lwT2) };
    float* nsrc = (float*)(ws + o_nsrc);
    float* ndst = (float*)(ws + o_ndst);
    int*   odeg8= (int*)(ws + o_odeg8);
    int*   roff = (int*)(ws + o_roff);
    int*   csr  = (int*)(ws + o_csr);
    unsigned int* stg = (unsigned int*)(ws + o_stg);
    int*   hist = (int*)(ws + o_hist);
    int*   boff = (int*)(ws + o_off);
    int*   bcnt = (int*)(ws + o_bcnt);
    int*   bbase= (int*)(ws + o_bbase);
    float* stats8 = (float*)(ws + o_stat8);
    int*   gst  = (int*)(ws + o_gst);
    float* hg   = (float*)(ws + o_hg);

    // zero accumulators
    zero_kernel<<<(8 * N_NODES + 255) / 256, 256, 0, stream>>>(odeg8, bcnt, stats8, hg);

    // edge pass 1: odeg + bucket histogram + bucket totals
    edge_pass1<<<NBUCK, 256, 0, stream>>>(src, dst, odeg8, hist, bcnt);

    // merged prep: nsrc + gstart + weight conversion
    misc_prep<<<(N_NODES + CVT_TOTAL + 255) / 256, 256, 0, stream>>>(
        odeg8, nsrc, gids, gst, w_init, lw[0], lw[1], lw[2], wB0, lwT[0], lwT[1], lwT[2]);

    // bucketed CSR build (XCD-local scatter)
    bscan_kernel<<<1, 512, 0, stream>>>(bcnt, bbase);
    boff_kernel<<<NBUCK, 512, 0, stream>>>(hist, bbase, boff);
    stage_kernel<<<NBUCK, 256, 0, stream>>>(src, dst, boff, stg);
    csr_kernel<<<NBUCK, 256, 0, stream>>>(stg, bbase, roff, ndst, csr);

    const int mblocks = (N_NODES + 127) / 128;

    // h0s = (h @ w_init^T) * nsrc   [N,128] bf16
    {
        dim3 grid(NCLS / 128, mblocks);
        mfma_gemm<true, false><<<grid, 256, 0, stream>>>(h, wB0, h0s, N_NODES, FIN, NCLS,
                                                         nsrc, nullptr, nullptr);
    }

    // ---- layer 0 ----
    agg128<<<AGG_BLOCKS, 256, 0, stream>>>(h0s, roff, csr, aggb);
    {
        dim3 grid(HID / 128, mblocks);
        mfma_gemm<false, true><<<grid, 256, 0, stream>>>(aggb, lwT[0], P, N_NODES, NCLS, HID,
                                                         ndst, lb[0], stats8 + 0 * 2 * HID);
    }

    // ---- layers 1,2 ----
    for (int l = 1; l < 3; l++) {
        bnq_kernel<<<1024, 256, 0, stream>>>(P, stats8 + (l - 1) * 2 * HID,
                                             gamma[l - 1], beta[l - 1], nsrc, Q);
        agg256<<<AGG_BLOCKS, 256, 0, stream>>>(Q, roff, csr, aggb);
        dim3 grid(HID / 128, mblocks);
        mfma_gemm<false, true><<<grid, 256, 0, stream>>>(aggb, lwT[l], P, N_NODES, HID, HID,
                                                         ndst, lb[l], stats8 + l * 2 * HID);
    }

    // ---- readout ----
    {
        dim3 grid(N_GRAPHS, 8);
        segmax_ab<<<grid, 256, 0, stream>>>(P, stats8 + 2 * 2 * HID, gamma[2], beta[2], gst, hg);
    }
    fc_kernel<<<(N_GRAPHS * OUT_DIM + 255) / 256, 256, 0, stream>>>(hg, fc_w, fc_b, out);
}

// Round 9
// 1134.847 us; speedup vs baseline: 1.0436x; 1.0436x over previous
//
#include <hip/hip_runtime.h>
#include <hip/hip_bf16.h>

#define N_NODES 100000
#define N_EDGES 3200000
#define N_GRAPHS 128
#define FIN 512
#define NCLS 128
#define HID 256
#define OUT_DIM 10
#define BN_EPS 1e-5f

#define NBUCK 391                      // ceil(N_NODES/256): bucket = dst >> 8
#define EPB   ((N_EDGES + NBUCK - 1) / NBUCK)   // edges per partition block
#define STATS_CPY 1536                 // 3 layers * 2 * HID, per-XCD copy stride

typedef unsigned short ush;
typedef ush su16x8 __attribute__((ext_vector_type(8)));
typedef ush su16x4 __attribute__((ext_vector_type(4)));
typedef __bf16 bf16x8v __attribute__((ext_vector_type(8)));
typedef float f32x4v __attribute__((ext_vector_type(4)));

__device__ __forceinline__ float bf2f(ush u) {
    union { unsigned int i; float f; } v; v.i = ((unsigned int)u) << 16; return v.f;
}
// native conversion: compiler emits v_cvt_pk_bf16_f32 for pairs (RNE)
__device__ __forceinline__ ush f2bf(float f) {
    __hip_bfloat16 b = __float2bfloat16(f);
    return __builtin_bit_cast(ush, b);
}

// MFMA shim: works whether the gfx950 builtin takes 16-bit-int vectors or __bf16 vectors.
template <typename T>
__device__ __forceinline__ auto mfma_sel(T a, T b, f32x4v c, int)
    -> decltype(__builtin_amdgcn_mfma_f32_16x16x32_bf16(a, b, c, 0, 0, 0)) {
    return __builtin_amdgcn_mfma_f32_16x16x32_bf16(a, b, c, 0, 0, 0);
}
template <typename T>
__device__ __forceinline__ f32x4v mfma_sel(T a, T b, f32x4v c, long) {
    return __builtin_amdgcn_mfma_f32_16x16x32_bf16(
        __builtin_bit_cast(bf16x8v, a), __builtin_bit_cast(bf16x8v, b), c, 0, 0, 0);
}
__device__ __forceinline__ f32x4v MFMA_BF16(su16x8 a, su16x8 b, f32x4v c) {
    return mfma_sel(a, b, c, 0);
}

// ---------------- zero pass ----------------
__global__ void zero_kernel(int* __restrict__ odeg8, int* __restrict__ bcnt,
                            float* __restrict__ stats8, float* __restrict__ hg) {
    int i = blockIdx.x * 256 + threadIdx.x;
    if (i < 8 * N_NODES) odeg8[i] = 0;
    if (i <= NBUCK) bcnt[i] = 0;
    if (i < 8 * STATS_CPY) stats8[i] = 0.f;
    if (i < N_GRAPHS * HID) hg[i] = 0.f;
}

// ---------------- edge pass 1: out-degree (8 XCD-local copies) + bucket histogram + bcnt ----------------
__global__ __launch_bounds__(256) void edge_pass1(const int* __restrict__ src,
                                                  const int* __restrict__ dst,
                                                  int* __restrict__ odeg8,
                                                  int* __restrict__ hist,
                                                  int* __restrict__ bcnt) {
    __shared__ int hc[NBUCK];
    int tid = threadIdx.x, blk = blockIdx.x;
    for (int i = tid; i < NBUCK; i += 256) hc[i] = 0;
    __syncthreads();
    int e0 = blk * EPB, e1 = e0 + EPB; if (e1 > N_EDGES) e1 = N_EDGES;
    int c = blk & 7;
    for (int e = e0 + tid; e < e1; e += 256) {
        atomicAdd(&odeg8[(size_t)c * N_NODES + src[e]], 1);
        atomicAdd(&hc[dst[e] >> 8], 1);
    }
    __syncthreads();
    for (int i = tid; i < NBUCK; i += 256) {
        int v = hc[i];
        hist[(size_t)blk * NBUCK + i] = v;
        if (v) atomicAdd(&bcnt[i], v);
    }
}

// ---------------- merged prep: nsrc + gstart + weight conversion ----------------
#define CVT_TOTAL (NCLS * FIN + HID * NCLS + HID * HID + HID * HID)
__global__ void misc_prep(const int* __restrict__ odeg8, float* __restrict__ nsrc,
                          const int* __restrict__ gids, int* __restrict__ gstart,
                          const float* __restrict__ w0, const float* __restrict__ l0,
                          const float* __restrict__ l1, const float* __restrict__ l2,
                          ush* __restrict__ wB0, ush* __restrict__ t0,
                          ush* __restrict__ t1, ush* __restrict__ t2) {
    int i = blockIdx.x * 256 + threadIdx.x;
    if (i < N_NODES) {
        int od = 0;
        #pragma unroll
        for (int c = 0; c < 8; c++) od += odeg8[(size_t)c * N_NODES + i];
        nsrc[i] = od > 0 ? rsqrtf((float)od) : 0.f;
        int g = gids[i];
        int gp = (i == 0) ? -1 : gids[i - 1];
        for (int gg = gp + 1; gg <= g; gg++) gstart[gg] = i;
        if (i == N_NODES - 1) {
            for (int gg = g + 1; gg <= N_GRAPHS; gg++) gstart[gg] = N_NODES;
        }
        return;
    }
    i -= N_NODES;
    if (i < NCLS * FIN) { wB0[i] = f2bf(w0[i]); return; }
    i -= NCLS * FIN;
    if (i < HID * NCLS) { int n = i >> 7, k = i & 127; t0[i] = f2bf(l0[k * HID + n]); return; }
    i -= HID * NCLS;
    if (i < HID * HID) { int n = i >> 8, k = i & 255; t1[i] = f2bf(l1[k * HID + n]); return; }
    i -= HID * HID;
    if (i < HID * HID) { int n = i >> 8, k = i & 255; t2[i] = f2bf(l2[k * HID + n]); }
}

// ---------------- pass Bscan — exclusive scan of bucket totals ----------------
__global__ __launch_bounds__(512) void bscan_kernel(const int* __restrict__ bcnt,
                                                    int* __restrict__ bbase) {
    __shared__ int a[512];
    int tid = threadIdx.x;
    int v = (tid < NBUCK) ? bcnt[tid] : 0;
    a[tid] = v;
    __syncthreads();
    for (int s = 1; s < 512; s <<= 1) {
        int y = (tid >= s) ? a[tid - s] : 0;
        __syncthreads();
        a[tid] += y;
        __syncthreads();
    }
    if (tid < NBUCK) bbase[tid] = a[tid] - v;
    if (tid == 0) bbase[NBUCK] = N_EDGES;
}

// ---------------- pass B2 — per-(block,bucket) offsets ----------------
__global__ __launch_bounds__(512) void boff_kernel(const int* __restrict__ hist,
                                                   const int* __restrict__ bbase,
                                                   int* __restrict__ off) {
    __shared__ int a[512];
    int b = blockIdx.x, tid = threadIdx.x;
    int v = (tid < NBUCK) ? hist[(size_t)tid * NBUCK + b] : 0;
    a[tid] = v;
    __syncthreads();
    for (int s = 1; s < 512; s <<= 1) {
        int y = (tid >= s) ? a[tid - s] : 0;
        __syncthreads();
        a[tid] += y;
        __syncthreads();
    }
    if (tid < NBUCK) off[(size_t)tid * NBUCK + b] = bbase[b] + a[tid] - v;
}

// ---------------- pass C — stage edges into bucket-contiguous runs ----------------
__global__ __launch_bounds__(256) void stage_kernel(const int* __restrict__ src,
                                                    const int* __restrict__ dst,
                                                    const int* __restrict__ off,
                                                    unsigned int* __restrict__ staged) {
    __shared__ int cur[NBUCK];
    int tid = threadIdx.x, blk = blockIdx.x;
    for (int i = tid; i < NBUCK; i += 256) cur[i] = off[(size_t)blk * NBUCK + i];
    __syncthreads();
    int e0 = blk * EPB, e1 = e0 + EPB; if (e1 > N_EDGES) e1 = N_EDGES;
    for (int e = e0 + tid; e < e1; e += 256) {
        int d = dst[e], s = src[e];
        int pos = atomicAdd(&cur[d >> 8], 1);
        staged[pos] = ((unsigned int)(d & 255) << 24) | (unsigned int)s;
    }
}

// ---------------- pass D — exact CSR within bucket + roff + ndst ----------------
__global__ __launch_bounds__(256) void csr_kernel(const unsigned int* __restrict__ staged,
                                                  const int* __restrict__ bbase,
                                                  int* __restrict__ roff,
                                                  float* __restrict__ ndst,
                                                  int* __restrict__ csr) {
    __shared__ int cnt[256], pfx[256], cur[256];
    int b = blockIdx.x, tid = threadIdx.x;
    int beg = bbase[b], end = bbase[b + 1];
    int nodeBase = b * 256;
    int nNodes = N_NODES - nodeBase; if (nNodes > 256) nNodes = 256;
    cnt[tid] = 0;
    __syncthreads();
    for (int e = beg + tid; e < end; e += 256) atomicAdd(&cnt[staged[e] >> 24], 1);
    __syncthreads();
    int v = cnt[tid];
    pfx[tid] = v;
    __syncthreads();
    for (int s = 1; s < 256; s <<= 1) {
        int y = (tid >= s) ? pfx[tid - s] : 0;
        __syncthreads();
        pfx[tid] += y;
        __syncthreads();
    }
    int excl = pfx[tid] - v;
    pfx[tid] = excl;
    cur[tid] = 0;
    if (tid < nNodes) {
        int node = nodeBase + tid;
        roff[node] = beg + excl;
        ndst[node] = v > 0 ? rsqrtf((float)v) : 0.f;
    }
    if (b == NBUCK - 1 && tid == 0) roff[N_NODES] = N_EDGES;
    __syncthreads();
    for (int e = beg + tid; e < end; e += 256) {
        unsigned int w = staged[e];
        int dl = w >> 24;
        int pos = beg + pfx[dl] + atomicAdd(&cur[dl], 1);
        csr[pos] = (int)(w & 0xFFFFFFu);
    }
}

// ---------------- MFMA GEMM: C[M,NN](bf16) = A[M,K] @ BT[NN,K]^T ----------------
template <bool A_F32, bool DO_STATS>
__global__ __launch_bounds__(256) void mfma_gemm(
    const void* __restrict__ Aptr, const ush* __restrict__ BT,
    ush* __restrict__ C, int M, int K, int NN,
    const float* __restrict__ rowscale, const float* __restrict__ bias,
    float* __restrict__ stats)
{
    __shared__ __align__(16) ush As[128][40];
    __shared__ __align__(16) ush Bs[128][40];
    const int bn0 = blockIdx.x * 128;
    const int bm0 = blockIdx.y * 128;
    const int tid = threadIdx.x;
    const int lane = tid & 63;
    const int wv = tid >> 6;
    const int wm = (wv >> 1) * 64;
    const int wn = (wv & 1) * 64;
    const int lm = lane & 15;
    const int lg = lane >> 4;

    f32x4v zero = {0.f, 0.f, 0.f, 0.f};
    f32x4v acc[4][4];
    #pragma unroll
    for (int mi = 0; mi < 4; mi++)
        #pragma unroll
        for (int ni = 0; ni < 4; ni++) acc[mi][ni] = zero;

    for (int k0 = 0; k0 < K; k0 += 32) {
        #pragma unroll
        for (int i = 0; i < 2; i++) {
            int seg = tid + i * 256;
            int n = seg >> 2, kp = seg & 3;
            su16x8 v = *(const su16x8*)&BT[(size_t)(bn0 + n) * K + k0 + kp * 8];
            *(su16x8*)&Bs[n][kp * 8] = v;
        }
        if constexpr (A_F32) {
            const float* Af = (const float*)Aptr;
            #pragma unroll
            for (int i = 0; i < 4; i++) {
                int seg = tid + i * 256;
                int m = seg >> 3, kp = seg & 7;
                int gm = bm0 + m; if (gm >= M) gm = M - 1;
                float4 v = *(const float4*)&Af[(size_t)gm * K + k0 + kp * 4];
                su16x4 o = { f2bf(v.x), f2bf(v.y), f2bf(v.z), f2bf(v.w) };
                *(su16x4*)&As[m][kp * 4] = o;
            }
        } else {
            const ush* Ab = (const ush*)Aptr;
            #pragma unroll
            for (int i = 0; i < 2; i++) {
                int seg = tid + i * 256;
                int m = seg >> 2, kp = seg & 3;
                int gm = bm0 + m; if (gm >= M) gm = M - 1;
                su16x8 v = *(const su16x8*)&Ab[(size_t)gm * K + k0 + kp * 8];
                *(su16x8*)&As[m][kp * 8] = v;
            }
        }
        __syncthreads();
        su16x8 af[4], bfr[4];
        #pragma unroll
        for (int i = 0; i < 4; i++)
            af[i] = *(const su16x8*)&As[wm + i * 16 + lm][lg * 8];
        #pragma unroll
        for (int i = 0; i < 4; i++)
            bfr[i] = *(const su16x8*)&Bs[wn + i * 16 + lm][lg * 8];
        #pragma unroll
        for (int mi = 0; mi < 4; mi++)
            #pragma unroll
            for (int ni = 0; ni < 4; ni++)
                acc[mi][ni] = MFMA_BF16(af[mi], bfr[ni], acc[mi][ni]);
        __syncthreads();
    }

    float s4[4] = {0.f, 0.f, 0.f, 0.f}, q4[4] = {0.f, 0.f, 0.f, 0.f};
    #pragma unroll
    for (int mi = 0; mi < 4; mi++) {
        #pragma unroll
        for (int j = 0; j < 4; j++) {
            int gm = bm0 + wm + mi * 16 + lg * 4 + j;
            bool valid = gm < M;
            float rs = (rowscale && valid) ? rowscale[gm] : 1.f;
            #pragma unroll
            for (int ni = 0; ni < 4; ni++) {
                int gn = bn0 + wn + ni * 16 + lm;
                float v = acc[mi][ni][j] * rs;
                if (bias) v += bias[gn];
                if (valid) {
                    C[(size_t)gm * NN + gn] = f2bf(v);
                    if constexpr (DO_STATS) { s4[ni] += v; q4[ni] += v * v; }
                }
            }
        }
    }
    if constexpr (DO_STATS) {
        float* st = stats + ((blockIdx.x + gridDim.x * blockIdx.y) & 7) * STATS_CPY;
        #pragma unroll
        for (int ni = 0; ni < 4; ni++) {
            s4[ni] += __shfl_xor(s4[ni], 16); s4[ni] += __shfl_xor(s4[ni], 32);
            q4[ni] += __shfl_xor(q4[ni], 16); q4[ni] += __shfl_xor(q4[ni], 32);
        }
        if (lg == 0) {
            #pragma unroll
            for (int ni = 0; ni < 4; ni++) {
                int gn = bn0 + wn + ni * 16 + lm;
                atomicAdd(&st[gn], s4[ni]);
                atomicAdd(&st[HID + gn], q4[ni]);
            }
        }
    }
}

// ---------------- BN prep: sum 8 stats copies -> per-channel scale/shift ----------------
__global__ void bnprep_kernel(const float* __restrict__ stats,
                              const float* __restrict__ gamma, const float* __restrict__ beta,
                              float* __restrict__ ab) {
    int c = threadIdx.x;   // 256
    float ssum = 0.f, qsum = 0.f;
    #pragma unroll
    for (int c8 = 0; c8 < 8; c8++) {
        ssum += stats[c8 * STATS_CPY + c];
        qsum += stats[c8 * STATS_CPY + HID + c];
    }
    const float inv_n = 1.f / (float)N_NODES;
    float mu = ssum * inv_n;
    float var = fmaf(-mu, mu, qsum * inv_n);
    float a = gamma[c] * rsqrtf(var + BN_EPS);
    ab[c] = a;
    ab[HID + c] = fmaf(-mu, a, beta[c]);
}

// ---------------- layer-0 aggregation (D=128): 4 contiguous slots/wave, unroll-4 (r6 body) ----------------
__global__ __launch_bounds__(256) void agg128(const ush* __restrict__ hs,
                                              const int* __restrict__ roff,
                                              const int* __restrict__ csr,
                                              ush* __restrict__ out)
{
    int node = (blockIdx.x * 256 + threadIdx.x) >> 6;
    int lane = threadIdx.x & 63;
    if (node >= N_NODES) return;
    int q = lane >> 4;
    int c0 = (lane & 15) * 8;
    int beg = roff[node], end = roff[node + 1];
    int len = end - beg;
    int s = beg + ((len * q) >> 2);
    int t = beg + ((len * (q + 1)) >> 2);
    float a0[8] = {}, a1[8] = {}, a2[8] = {}, a3[8] = {};
    int e = s;
    for (; e + 3 < t; e += 4) {
        int i0 = __builtin_nontemporal_load(&csr[e]);
        int i1 = __builtin_nontemporal_load(&csr[e + 1]);
        int i2 = __builtin_nontemporal_load(&csr[e + 2]);
        int i3 = __builtin_nontemporal_load(&csr[e + 3]);
        su16x8 v0 = *(const su16x8*)&hs[(size_t)i0 * 128 + c0];
        su16x8 v1 = *(const su16x8*)&hs[(size_t)i1 * 128 + c0];
        su16x8 v2 = *(const su16x8*)&hs[(size_t)i2 * 128 + c0];
        su16x8 v3 = *(const su16x8*)&hs[(size_t)i3 * 128 + c0];
        #pragma unroll
        for (int j = 0; j < 8; j++) {
            a0[j] += bf2f(v0[j]); a1[j] += bf2f(v1[j]);
            a2[j] += bf2f(v2[j]); a3[j] += bf2f(v3[j]);
        }
    }
    for (; e < t; e++) {
        int i0 = __builtin_nontemporal_load(&csr[e]);
        su16x8 v0 = *(const su16x8*)&hs[(size_t)i0 * 128 + c0];
        #pragma unroll
        for (int j = 0; j < 8; j++) a0[j] += bf2f(v0[j]);
    }
    #pragma unroll
    for (int j = 0; j < 8; j++) {
        a0[j] += a1[j] + a2[j] + a3[j];
        a0[j] += __shfl_xor(a0[j], 16);
        a0[j] += __shfl_xor(a0[j], 32);
    }
    if (lane < 16) {
        su16x8 o;
        #pragma unroll
        for (int j = 0; j < 8; j++) o[j] = f2bf(a0[j]);
        __builtin_nontemporal_store(o, (su16x8*)&out[(size_t)node * 128 + c0]);
    }
}

// ---------------- layers 1,2: fused agg over relu(BN(P))*nsrc (r6 body + BN on read) ----------------
__global__ __launch_bounds__(256) void agg256_bn(const ush* __restrict__ P,
                                                 const float* __restrict__ bnab,
                                                 const float* __restrict__ nsrc,
                                                 const int* __restrict__ roff,
                                                 const int* __restrict__ csr,
                                                 ush* __restrict__ out)
{
    int node = (blockIdx.x * 256 + threadIdx.x) >> 6;
    int lane = threadIdx.x & 63;
    if (node >= N_NODES) return;
    int half = lane >> 5;
    int c0 = (lane & 31) * 8;
    float ca[8], cb[8];
    {
        f32x4v a0v = *(const f32x4v*)&bnab[c0];
        f32x4v a1v = *(const f32x4v*)&bnab[c0 + 4];
        f32x4v b0v = *(const f32x4v*)&bnab[HID + c0];
        f32x4v b1v = *(const f32x4v*)&bnab[HID + c0 + 4];
        #pragma unroll
        for (int j = 0; j < 4; j++) { ca[j] = a0v[j]; ca[4 + j] = a1v[j]; cb[j] = b0v[j]; cb[4 + j] = b1v[j]; }
    }
    int beg = roff[node], end = roff[node + 1];
    int len = end - beg;
    int s = beg + ((len * half) >> 1);
    int t = beg + ((len * (half + 1)) >> 1);
    float a0[8] = {}, a1[8] = {}, a2[8] = {}, a3[8] = {};
    int e = s;
    for (; e + 3 < t; e += 4) {
        int i0 = __builtin_nontemporal_load(&csr[e]);
        int i1 = __builtin_nontemporal_load(&csr[e + 1]);
        int i2 = __builtin_nontemporal_load(&csr[e + 2]);
        int i3 = __builtin_nontemporal_load(&csr[e + 3]);
        float n0 = nsrc[i0], n1 = nsrc[i1], n2 = nsrc[i2], n3 = nsrc[i3];
        su16x8 v0 = *(const su16x8*)&P[(size_t)i0 * 256 + c0];
        su16x8 v1 = *(const su16x8*)&P[(size_t)i1 * 256 + c0];
        su16x8 v2 = *(const su16x8*)&P[(size_t)i2 * 256 + c0];
        su16x8 v3 = *(const su16x8*)&P[(size_t)i3 * 256 + c0];
        #pragma unroll
        for (int j = 0; j < 8; j++) {
            float x0 = fmaxf(fmaf(bf2f(v0[j]), ca[j], cb[j]), 0.f);
            float x1 = fmaxf(fmaf(bf2f(v1[j]), ca[j], cb[j]), 0.f);
            float x2 = fmaxf(fmaf(bf2f(v2[j]), ca[j], cb[j]), 0.f);
            float x3 = fmaxf(fmaf(bf2f(v3[j]), ca[j], cb[j]), 0.f);
            a0[j] = fmaf(x0, n0, a0[j]); a1[j] = fmaf(x1, n1, a1[j]);
            a2[j] = fmaf(x2, n2, a2[j]); a3[j] = fmaf(x3, n3, a3[j]);
        }
    }
    for (; e < t; e++) {
        int i0 = __builtin_nontemporal_load(&csr[e]);
        float n0 = nsrc[i0];
        su16x8 v0 = *(const su16x8*)&P[(size_t)i0 * 256 + c0];
        #pragma unroll
        for (int j = 0; j < 8; j++) {
            float x0 = fmaxf(fmaf(bf2f(v0[j]), ca[j], cb[j]), 0.f);
            a0[j] = fmaf(x0, n0, a0[j]);
        }
    }
    #pragma unroll
    for (int j = 0; j < 8; j++) {
        a0[j] += a1[j] + a2[j] + a3[j];
        a0[j] += __shfl_xor(a0[j], 32);
    }
    if (lane < 32) {
        su16x8 o;
        #pragma unroll
        for (int j = 0; j < 8; j++) o[j] = f2bf(a0[j]);
        __builtin_nontemporal_store(o, (su16x8*)&out[(size_t)node * 256 + c0]);
    }
}

// ---------------- per-graph max with fused BN+ReLU (hg pre-zeroed) ----------------
__global__ __launch_bounds__(256) void segmax_ab(const ush* __restrict__ pre,
                                                 const float* __restrict__ bnab,
                                                 const int* __restrict__ gstart,
                                                 float* __restrict__ hg) {
    int c = threadIdx.x;
    float a = bnab[c], b = bnab[HID + c];
    int g = blockIdx.x;
    int chunk = blockIdx.y;
    int beg = gstart[g], end = gstart[g + 1];
    int len = end - beg;
    int per = (len + 7) >> 3;
    int s = beg + chunk * per;
    int e = s + per; if (e > end) e = end;
    float m0 = 0.f, m1 = 0.f;
    int n = s;
    for (; n + 1 < e; n += 2) {
        m0 = fmaxf(m0, fmaf(bf2f(pre[(size_t)n * HID + c]), a, b));
        m1 = fmaxf(m1, fmaf(bf2f(pre[(size_t)(n + 1) * HID + c]), a, b));
    }
    if (n < e) m0 = fmaxf(m0, fmaf(bf2f(pre[(size_t)n * HID + c]), a, b));
    float m = fmaxf(fmaxf(m0, m1), 0.f);
    atomicMax((int*)&hg[g * HID + c], __float_as_int(m));
}

// ---------------- final fc ----------------
__global__ void fc_kernel(const float* __restrict__ hg, const float* __restrict__ w,
                          const float* __restrict__ b, float* __restrict__ out) {
    int idx = blockIdx.x * 256 + threadIdx.x;
    if (idx >= N_GRAPHS * OUT_DIM) return;
    int g = idx / OUT_DIM, j = idx % OUT_DIM;
    float s = b[j];
    for (int c = 0; c < HID; c++) s += hg[g * HID + c] * w[c * OUT_DIM + j];
    out[idx] = s;
}

extern "C" void kernel_launch(void* const* d_in, const int* in_sizes, int n_in,
                              void* d_out, int out_size, void* d_ws, size_t ws_size,
                              hipStream_t stream) {
    const float* h      = (const float*)d_in[0];
    const int*   src    = (const int*)d_in[1];
    const int*   dst    = (const int*)d_in[2];
    const int*   gids   = (const int*)d_in[3];
    const float* w_init = (const float*)d_in[4];
    const float* lw[3]    = { (const float*)d_in[5],  (const float*)d_in[9],  (const float*)d_in[13] };
    const float* lb[3]    = { (const float*)d_in[6],  (const float*)d_in[10], (const float*)d_in[14] };
    const float* gamma[3] = { (const float*)d_in[7],  (const float*)d_in[11], (const float*)d_in[15] };
    const float* beta[3]  = { (const float*)d_in[8],  (const float*)d_in[12], (const float*)d_in[16] };
    const float* fc_w = (const float*)d_in[17];
    const float* fc_b = (const float*)d_in[18];
    float* out = (float*)d_out;

    // ---- workspace layout ----
    char* ws = (char*)d_ws;
    size_t off_b = 0;
    auto alloc = [&](size_t bytes) { size_t o = off_b; off_b += (bytes + 255) & ~(size_t)255; return o; };
    size_t o_h0s   = alloc((size_t)N_NODES * NCLS * 2);
    size_t o_aggb  = alloc((size_t)N_NODES * HID * 2);
    size_t o_P     = alloc((size_t)N_NODES * HID * 2);
    size_t o_wB0   = alloc((size_t)NCLS * FIN * 2);
    size_t o_lwT0  = alloc((size_t)HID * NCLS * 2);
    size_t o_lwT1  = alloc((size_t)HID * HID * 2);
    size_t o_lwT2  = alloc((size_t)HID * HID * 2);
    size_t o_nsrc  = alloc((size_t)N_NODES * 4);
    size_t o_ndst  = alloc((size_t)N_NODES * 4);
    size_t o_odeg8 = alloc((size_t)8 * N_NODES * 4);
    size_t o_roff  = alloc((size_t)(N_NODES + 1) * 4);
    size_t o_csr   = alloc((size_t)N_EDGES * 4);
    size_t o_stg   = alloc((size_t)N_EDGES * 4);
    size_t o_hist  = alloc((size_t)NBUCK * NBUCK * 4);
    size_t o_off   = alloc((size_t)NBUCK * NBUCK * 4);
    size_t o_bcnt  = alloc((size_t)(NBUCK + 1) * 4);
    size_t o_bbase = alloc((size_t)(NBUCK + 1) * 4);
    size_t o_stat8 = alloc((size_t)8 * STATS_CPY * 4);
    size_t o_bnab  = alloc((size_t)3 * 2 * HID * 4);
    size_t o_gst   = alloc((size_t)(N_GRAPHS + 1) * 4);
    size_t o_hg    = alloc((size_t)N_GRAPHS * HID * 4);
    if (off_b > ws_size) return;

    ush*   h0s  = (ush*)(ws + o_h0s);
    ush*   aggb = (ush*)(ws + o_aggb);
    ush*   P    = (ush*)(ws + o_P);
    ush*   wB0  = (ush*)(ws + o_wB0);
    ush*   lwT[3] = { (ush*)(ws + o_lwT0), (ush*)(ws + o_lwT1), (ush*)(ws + o_lwT2) };
    float* nsrc = (float*)(ws + o_nsrc);
    float* ndst = (float*)(ws + o_ndst);
    int*   odeg8= (int*)(ws + o_odeg8);
    int*   roff = (int*)(ws + o_roff);
    int*   csr  = (int*)(ws + o_csr);
    unsigned int* stg = (unsigned int*)(ws + o_stg);
    int*   hist = (int*)(ws + o_hist);
    int*   boff = (int*)(ws + o_off);
    int*   bcnt = (int*)(ws + o_bcnt);
    int*   bbase= (int*)(ws + o_bbase);
    float* stats8 = (float*)(ws + o_stat8);
    float* bnab = (float*)(ws + o_bnab);
    int*   gst  = (int*)(ws + o_gst);
    float* hg   = (float*)(ws + o_hg);

    // zero accumulators
    zero_kernel<<<(8 * N_NODES + 255) / 256, 256, 0, stream>>>(odeg8, bcnt, stats8, hg);

    // edge pass 1: odeg + bucket histogram + bucket totals
    edge_pass1<<<NBUCK, 256, 0, stream>>>(src, dst, odeg8, hist, bcnt);

    // merged prep: nsrc + gstart + weight conversion
    misc_prep<<<(N_NODES + CVT_TOTAL + 255) / 256, 256, 0, stream>>>(
        odeg8, nsrc, gids, gst, w_init, lw[0], lw[1], lw[2], wB0, lwT[0], lwT[1], lwT[2]);

    // bucketed CSR build (XCD-local scatter)
    bscan_kernel<<<1, 512, 0, stream>>>(bcnt, bbase);
    boff_kernel<<<NBUCK, 512, 0, stream>>>(hist, bbase, boff);
    stage_kernel<<<NBUCK, 256, 0, stream>>>(src, dst, boff, stg);
    csr_kernel<<<NBUCK, 256, 0, stream>>>(stg, bbase, roff, ndst, csr);

    const int mblocks = (N_NODES + 127) / 128;
    const int aggblocks = (N_NODES * 64 + 255) / 256;

    // h0s = (h @ w_init^T) * nsrc   [N,128] bf16
    {
        dim3 grid(NCLS / 128, mblocks);
        mfma_gemm<true, false><<<grid, 256, 0, stream>>>(h, wB0, h0s, N_NODES, FIN, NCLS,
                                                         nsrc, nullptr, nullptr);
    }

    // ---- layer 0 ----
    agg128<<<aggblocks, 256, 0, stream>>>(h0s, roff, csr, aggb);
    {
        dim3 grid(HID / 128, mblocks);
        mfma_gemm<false, true><<<grid, 256, 0, stream>>>(aggb, lwT[0], P, N_NODES, NCLS, HID,
                                                         ndst, lb[0], stats8 + 0 * 2 * HID);
    }

    // ---- layers 1,2 ----
    for (int l = 1; l < 3; l++) {
        bnprep_kernel<<<1, 256, 0, stream>>>(stats8 + (l - 1) * 2 * HID,
                                             gamma[l - 1], beta[l - 1], bnab + (l - 1) * 2 * HID);
        agg256_bn<<<aggblocks, 256, 0, stream>>>(P, bnab + (l - 1) * 2 * HID, nsrc,
                                                 roff, csr, aggb);
        dim3 grid(HID / 128, mblocks);
        mfma_gemm<false, true><<<grid, 256, 0, stream>>>(aggb, lwT[l], P, N_NODES, HID, HID,
                                                         ndst, lb[l], stats8 + l * 2 * HID);
    }

    // ---- readout ----
    bnprep_kernel<<<1, 256, 0, stream>>>(stats8 + 2 * 2 * HID, gamma[2], beta[2],
                                         bnab + 2 * 2 * HID);
    {
        dim3 grid(N_GRAPHS, 8);
        segmax_ab<<<grid, 256, 0, stream>>>(P, bnab + 2 * 2 * HID, gst, hg);
    }
    fc_kernel<<<(N_GRAPHS * OUT_DIM + 255) / 256, 256, 0, stream>>>(hg, fc_w, fc_b, out);
}

// Round 10
// 1072.229 us; speedup vs baseline: 1.1045x; 1.0584x over previous
//
#include <hip/hip_runtime.h>
#include <hip/hip_bf16.h>

#define N_NODES 100000
#define N_EDGES 3200000
#define N_GRAPHS 128
#define FIN 512
#define NCLS 128
#define HID 256
#define OUT_DIM 10
#define BN_EPS 1e-5f

#define NBUCK 391                      // ceil(N_NODES/256): bucket = dst >> 8
#define EPB   ((N_EDGES + NBUCK - 1) / NBUCK)   // edges per partition block
#define STATS_CPY 1536                 // 3 layers * 2 * HID, per-XCD copy stride

typedef unsigned short ush;
typedef ush su16x8 __attribute__((ext_vector_type(8)));
typedef ush su16x4 __attribute__((ext_vector_type(4)));
typedef __bf16 bf16x8v __attribute__((ext_vector_type(8)));
typedef float f32x4v __attribute__((ext_vector_type(4)));

__device__ __forceinline__ float bf2f(ush u) {
    union { unsigned int i; float f; } v; v.i = ((unsigned int)u) << 16; return v.f;
}
// native conversion: compiler emits v_cvt_pk_bf16_f32 for pairs (RNE)
__device__ __forceinline__ ush f2bf(float f) {
    __hip_bfloat16 b = __float2bfloat16(f);
    return __builtin_bit_cast(ush, b);
}

// MFMA shim: works whether the gfx950 builtin takes 16-bit-int vectors or __bf16 vectors.
template <typename T>
__device__ __forceinline__ auto mfma_sel(T a, T b, f32x4v c, int)
    -> decltype(__builtin_amdgcn_mfma_f32_16x16x32_bf16(a, b, c, 0, 0, 0)) {
    return __builtin_amdgcn_mfma_f32_16x16x32_bf16(a, b, c, 0, 0, 0);
}
template <typename T>
__device__ __forceinline__ f32x4v mfma_sel(T a, T b, f32x4v c, long) {
    return __builtin_amdgcn_mfma_f32_16x16x32_bf16(
        __builtin_bit_cast(bf16x8v, a), __builtin_bit_cast(bf16x8v, b), c, 0, 0, 0);
}
__device__ __forceinline__ f32x4v MFMA_BF16(su16x8 a, su16x8 b, f32x4v c) {
    return mfma_sel(a, b, c, 0);
}

// ---------------- zero pass ----------------
__global__ void zero_kernel(int* __restrict__ odeg8, int* __restrict__ bcnt,
                            float* __restrict__ stats8, float* __restrict__ hg) {
    int i = blockIdx.x * 256 + threadIdx.x;
    if (i < 8 * N_NODES) odeg8[i] = 0;
    if (i <= NBUCK) bcnt[i] = 0;
    if (i < 8 * STATS_CPY) stats8[i] = 0.f;
    if (i < N_GRAPHS * HID) hg[i] = 0.f;
}

// ---------------- edge pass 1: out-degree (8 XCD-local copies) + bucket histogram + bcnt ----------------
__global__ __launch_bounds__(256) void edge_pass1(const int* __restrict__ src,
                                                  const int* __restrict__ dst,
                                                  int* __restrict__ odeg8,
                                                  int* __restrict__ hist,
                                                  int* __restrict__ bcnt) {
    __shared__ int hc[NBUCK];
    int tid = threadIdx.x, blk = blockIdx.x;
    for (int i = tid; i < NBUCK; i += 256) hc[i] = 0;
    __syncthreads();
    int e0 = blk * EPB, e1 = e0 + EPB; if (e1 > N_EDGES) e1 = N_EDGES;
    int c = blk & 7;
    for (int e = e0 + tid; e < e1; e += 256) {
        atomicAdd(&odeg8[(size_t)c * N_NODES + src[e]], 1);
        atomicAdd(&hc[dst[e] >> 8], 1);
    }
    __syncthreads();
    for (int i = tid; i < NBUCK; i += 256) {
        int v = hc[i];
        hist[(size_t)blk * NBUCK + i] = v;
        if (v) atomicAdd(&bcnt[i], v);
    }
}

// ---------------- merged prep: nsrc + gstart + weight conversion ----------------
#define CVT_TOTAL (NCLS * FIN + HID * NCLS + HID * HID + HID * HID)
__global__ void misc_prep(const int* __restrict__ odeg8, float* __restrict__ nsrc,
                          const int* __restrict__ gids, int* __restrict__ gstart,
                          const float* __restrict__ w0, const float* __restrict__ l0,
                          const float* __restrict__ l1, const float* __restrict__ l2,
                          ush* __restrict__ wB0, ush* __restrict__ t0,
                          ush* __restrict__ t1, ush* __restrict__ t2) {
    int i = blockIdx.x * 256 + threadIdx.x;
    if (i < N_NODES) {
        int od = 0;
        #pragma unroll
        for (int c = 0; c < 8; c++) od += odeg8[(size_t)c * N_NODES + i];
        nsrc[i] = od > 0 ? rsqrtf((float)od) : 0.f;
        int g = gids[i];
        int gp = (i == 0) ? -1 : gids[i - 1];
        for (int gg = gp + 1; gg <= g; gg++) gstart[gg] = i;
        if (i == N_NODES - 1) {
            for (int gg = g + 1; gg <= N_GRAPHS; gg++) gstart[gg] = N_NODES;
        }
        return;
    }
    i -= N_NODES;
    if (i < NCLS * FIN) { wB0[i] = f2bf(w0[i]); return; }
    i -= NCLS * FIN;
    if (i < HID * NCLS) { int n = i >> 7, k = i & 127; t0[i] = f2bf(l0[k * HID + n]); return; }
    i -= HID * NCLS;
    if (i < HID * HID) { int n = i >> 8, k = i & 255; t1[i] = f2bf(l1[k * HID + n]); return; }
    i -= HID * HID;
    if (i < HID * HID) { int n = i >> 8, k = i & 255; t2[i] = f2bf(l2[k * HID + n]); }
}

// ---------------- pass Bscan — exclusive scan of bucket totals ----------------
__global__ __launch_bounds__(512) void bscan_kernel(const int* __restrict__ bcnt,
                                                    int* __restrict__ bbase) {
    __shared__ int a[512];
    int tid = threadIdx.x;
    int v = (tid < NBUCK) ? bcnt[tid] : 0;
    a[tid] = v;
    __syncthreads();
    for (int s = 1; s < 512; s <<= 1) {
        int y = (tid >= s) ? a[tid - s] : 0;
        __syncthreads();
        a[tid] += y;
        __syncthreads();
    }
    if (tid < NBUCK) bbase[tid] = a[tid] - v;
    if (tid == 0) bbase[NBUCK] = N_EDGES;
}

// ---------------- pass B2 — per-(block,bucket) offsets ----------------
__global__ __launch_bounds__(512) void boff_kernel(const int* __restrict__ hist,
                                                   const int* __restrict__ bbase,
                                                   int* __restrict__ off) {
    __shared__ int a[512];
    int b = blockIdx.x, tid = threadIdx.x;
    int v = (tid < NBUCK) ? hist[(size_t)tid * NBUCK + b] : 0;
    a[tid] = v;
    __syncthreads();
    for (int s = 1; s < 512; s <<= 1) {
        int y = (tid >= s) ? a[tid - s] : 0;
        __syncthreads();
        a[tid] += y;
        __syncthreads();
    }
    if (tid < NBUCK) off[(size_t)tid * NBUCK + b] = bbase[b] + a[tid] - v;
}

// ---------------- pass C — stage edges into bucket-contiguous runs ----------------
__global__ __launch_bounds__(256) void stage_kernel(const int* __restrict__ src,
                                                    const int* __restrict__ dst,
                                                    const int* __restrict__ off,
                                                    unsigned int* __restrict__ staged) {
    __shared__ int cur[NBUCK];
    int tid = threadIdx.x, blk = blockIdx.x;
    for (int i = tid; i < NBUCK; i += 256) cur[i] = off[(size_t)blk * NBUCK + i];
    __syncthreads();
    int e0 = blk * EPB, e1 = e0 + EPB; if (e1 > N_EDGES) e1 = N_EDGES;
    for (int e = e0 + tid; e < e1; e += 256) {
        int d = dst[e], s = src[e];
        int pos = atomicAdd(&cur[d >> 8], 1);
        staged[pos] = ((unsigned int)(d & 255) << 24) | (unsigned int)s;
    }
}

// ---------------- pass D — exact CSR within bucket + roff + ndst ----------------
__global__ __launch_bounds__(256) void csr_kernel(const unsigned int* __restrict__ staged,
                                                  const int* __restrict__ bbase,
                                                  int* __restrict__ roff,
                                                  float* __restrict__ ndst,
                                                  int* __restrict__ csr) {
    __shared__ int cnt[256], pfx[256], cur[256];
    int b = blockIdx.x, tid = threadIdx.x;
    int beg = bbase[b], end = bbase[b + 1];
    int nodeBase = b * 256;
    int nNodes = N_NODES - nodeBase; if (nNodes > 256) nNodes = 256;
    cnt[tid] = 0;
    __syncthreads();
    for (int e = beg + tid; e < end; e += 256) atomicAdd(&cnt[staged[e] >> 24], 1);
    __syncthreads();
    int v = cnt[tid];
    pfx[tid] = v;
    __syncthreads();
    for (int s = 1; s < 256; s <<= 1) {
        int y = (tid >= s) ? pfx[tid - s] : 0;
        __syncthreads();
        pfx[tid] += y;
        __syncthreads();
    }
    int excl = pfx[tid] - v;
    pfx[tid] = excl;
    cur[tid] = 0;
    if (tid < nNodes) {
        int node = nodeBase + tid;
        roff[node] = beg + excl;
        ndst[node] = v > 0 ? rsqrtf((float)v) : 0.f;
    }
    if (b == NBUCK - 1 && tid == 0) roff[N_NODES] = N_EDGES;
    __syncthreads();
    for (int e = beg + tid; e < end; e += 256) {
        unsigned int w = staged[e];
        int dl = w >> 24;
        int pos = beg + pfx[dl] + atomicAdd(&cur[dl], 1);
        csr[pos] = (int)(w & 0xFFFFFFu);
    }
}

// ---------------- MFMA GEMM: C[M,NN](bf16) = A[M,K] @ BT[NN,K]^T ----------------
template <bool A_F32, bool DO_STATS>
__global__ __launch_bounds__(256) void mfma_gemm(
    const void* __restrict__ Aptr, const ush* __restrict__ BT,
    ush* __restrict__ C, int M, int K, int NN,
    const float* __restrict__ rowscale, const float* __restrict__ bias,
    float* __restrict__ stats)
{
    __shared__ __align__(16) ush As[128][40];
    __shared__ __align__(16) ush Bs[128][40];
    const int bn0 = blockIdx.x * 128;
    const int bm0 = blockIdx.y * 128;
    const int tid = threadIdx.x;
    const int lane = tid & 63;
    const int wv = tid >> 6;
    const int wm = (wv >> 1) * 64;
    const int wn = (wv & 1) * 64;
    const int lm = lane & 15;
    const int lg = lane >> 4;

    f32x4v zero = {0.f, 0.f, 0.f, 0.f};
    f32x4v acc[4][4];
    #pragma unroll
    for (int mi = 0; mi < 4; mi++)
        #pragma unroll
        for (int ni = 0; ni < 4; ni++) acc[mi][ni] = zero;

    for (int k0 = 0; k0 < K; k0 += 32) {
        #pragma unroll
        for (int i = 0; i < 2; i++) {
            int seg = tid + i * 256;
            int n = seg >> 2, kp = seg & 3;
            su16x8 v = *(const su16x8*)&BT[(size_t)(bn0 + n) * K + k0 + kp * 8];
            *(su16x8*)&Bs[n][kp * 8] = v;
        }
        if constexpr (A_F32) {
            const float* Af = (const float*)Aptr;
            #pragma unroll
            for (int i = 0; i < 4; i++) {
                int seg = tid + i * 256;
                int m = seg >> 3, kp = seg & 7;
                int gm = bm0 + m; if (gm >= M) gm = M - 1;
                float4 v = *(const float4*)&Af[(size_t)gm * K + k0 + kp * 4];
                su16x4 o = { f2bf(v.x), f2bf(v.y), f2bf(v.z), f2bf(v.w) };
                *(su16x4*)&As[m][kp * 4] = o;
            }
        } else {
            const ush* Ab = (const ush*)Aptr;
            #pragma unroll
            for (int i = 0; i < 2; i++) {
                int seg = tid + i * 256;
                int m = seg >> 2, kp = seg & 3;
                int gm = bm0 + m; if (gm >= M) gm = M - 1;
                su16x8 v = *(const su16x8*)&Ab[(size_t)gm * K + k0 + kp * 8];
                *(su16x8*)&As[m][kp * 8] = v;
            }
        }
        __syncthreads();
        su16x8 af[4], bfr[4];
        #pragma unroll
        for (int i = 0; i < 4; i++)
            af[i] = *(const su16x8*)&As[wm + i * 16 + lm][lg * 8];
        #pragma unroll
        for (int i = 0; i < 4; i++)
            bfr[i] = *(const su16x8*)&Bs[wn + i * 16 + lm][lg * 8];
        #pragma unroll
        for (int mi = 0; mi < 4; mi++)
            #pragma unroll
            for (int ni = 0; ni < 4; ni++)
                acc[mi][ni] = MFMA_BF16(af[mi], bfr[ni], acc[mi][ni]);
        __syncthreads();
    }

    float s4[4] = {0.f, 0.f, 0.f, 0.f}, q4[4] = {0.f, 0.f, 0.f, 0.f};
    #pragma unroll
    for (int mi = 0; mi < 4; mi++) {
        #pragma unroll
        for (int j = 0; j < 4; j++) {
            int gm = bm0 + wm + mi * 16 + lg * 4 + j;
            bool valid = gm < M;
            float rs = (rowscale && valid) ? rowscale[gm] : 1.f;
            #pragma unroll
            for (int ni = 0; ni < 4; ni++) {
                int gn = bn0 + wn + ni * 16 + lm;
                float v = acc[mi][ni][j] * rs;
                if (bias) v += bias[gn];
                if (valid) {
                    C[(size_t)gm * NN + gn] = f2bf(v);
                    if constexpr (DO_STATS) { s4[ni] += v; q4[ni] += v * v; }
                }
            }
        }
    }
    if constexpr (DO_STATS) {
        float* st = stats + ((blockIdx.x + gridDim.x * blockIdx.y) & 7) * STATS_CPY;
        #pragma unroll
        for (int ni = 0; ni < 4; ni++) {
            s4[ni] += __shfl_xor(s4[ni], 16); s4[ni] += __shfl_xor(s4[ni], 32);
            q4[ni] += __shfl_xor(q4[ni], 16); q4[ni] += __shfl_xor(q4[ni], 32);
        }
        if (lg == 0) {
            #pragma unroll
            for (int ni = 0; ni < 4; ni++) {
                int gn = bn0 + wn + ni * 16 + lm;
                atomicAdd(&st[gn], s4[ni]);
                atomicAdd(&st[HID + gn], q4[ni]);
            }
        }
    }
}

// ---------------- layer-0 aggregation (D=128): 4 contiguous slots/wave, unroll-4 (r6 body) ----------------
__global__ __launch_bounds__(256) void agg128(const ush* __restrict__ hs,
                                              const int* __restrict__ roff,
                                              const int* __restrict__ csr,
                                              ush* __restrict__ out)
{
    int node = (blockIdx.x * 256 + threadIdx.x) >> 6;
    int lane = threadIdx.x & 63;
    if (node >= N_NODES) return;
    int q = lane >> 4;
    int c0 = (lane & 15) * 8;
    int beg = roff[node], end = roff[node + 1];
    int len = end - beg;
    int s = beg + ((len * q) >> 2);
    int t = beg + ((len * (q + 1)) >> 2);
    float a0[8] = {}, a1[8] = {}, a2[8] = {}, a3[8] = {};
    int e = s;
    for (; e + 3 < t; e += 4) {
        int i0 = csr[e], i1 = csr[e + 1], i2 = csr[e + 2], i3 = csr[e + 3];
        su16x8 v0 = *(const su16x8*)&hs[(size_t)i0 * 128 + c0];
        su16x8 v1 = *(const su16x8*)&hs[(size_t)i1 * 128 + c0];
        su16x8 v2 = *(const su16x8*)&hs[(size_t)i2 * 128 + c0];
        su16x8 v3 = *(const su16x8*)&hs[(size_t)i3 * 128 + c0];
        #pragma unroll
        for (int j = 0; j < 8; j++) {
            a0[j] += bf2f(v0[j]); a1[j] += bf2f(v1[j]);
            a2[j] += bf2f(v2[j]); a3[j] += bf2f(v3[j]);
        }
    }
    for (; e < t; e++) {
        int i0 = csr[e];
        su16x8 v0 = *(const su16x8*)&hs[(size_t)i0 * 128 + c0];
        #pragma unroll
        for (int j = 0; j < 8; j++) a0[j] += bf2f(v0[j]);
    }
    #pragma unroll
    for (int j = 0; j < 8; j++) {
        a0[j] += a1[j] + a2[j] + a3[j];
        a0[j] += __shfl_xor(a0[j], 16);
        a0[j] += __shfl_xor(a0[j], 32);
    }
    if (lane < 16) {
        su16x8 o;
        #pragma unroll
        for (int j = 0; j < 8; j++) o[j] = f2bf(a0[j]);
        __builtin_nontemporal_store(o, (su16x8*)&out[(size_t)node * 128 + c0]);
    }
}

// ---------------- layers 1,2 aggregation (D=256): 2 contiguous slots/wave, unroll-4 (r6 body) ----------------
__global__ __launch_bounds__(256) void agg256(const ush* __restrict__ Q,
                                              const int* __restrict__ roff,
                                              const int* __restrict__ csr,
                                              ush* __restrict__ out)
{
    int node = (blockIdx.x * 256 + threadIdx.x) >> 6;
    int lane = threadIdx.x & 63;
    if (node >= N_NODES) return;
    int half = lane >> 5;
    int c0 = (lane & 31) * 8;
    int beg = roff[node], end = roff[node + 1];
    int len = end - beg;
    int s = beg + ((len * half) >> 1);
    int t = beg + ((len * (half + 1)) >> 1);
    float a0[8] = {}, a1[8] = {}, a2[8] = {}, a3[8] = {};
    int e = s;
    for (; e + 3 < t; e += 4) {
        int i0 = csr[e], i1 = csr[e + 1], i2 = csr[e + 2], i3 = csr[e + 3];
        su16x8 v0 = *(const su16x8*)&Q[(size_t)i0 * 256 + c0];
        su16x8 v1 = *(const su16x8*)&Q[(size_t)i1 * 256 + c0];
        su16x8 v2 = *(const su16x8*)&Q[(size_t)i2 * 256 + c0];
        su16x8 v3 = *(const su16x8*)&Q[(size_t)i3 * 256 + c0];
        #pragma unroll
        for (int j = 0; j < 8; j++) {
            a0[j] += bf2f(v0[j]); a1[j] += bf2f(v1[j]);
            a2[j] += bf2f(v2[j]); a3[j] += bf2f(v3[j]);
        }
    }
    for (; e < t; e++) {
        int i0 = csr[e];
        su16x8 v0 = *(const su16x8*)&Q[(size_t)i0 * 256 + c0];
        #pragma unroll
        for (int j = 0; j < 8; j++) a0[j] += bf2f(v0[j]);
    }
    #pragma unroll
    for (int j = 0; j < 8; j++) {
        a0[j] += a1[j] + a2[j] + a3[j];
        a0[j] += __shfl_xor(a0[j], 32);
    }
    if (lane < 32) {
        su16x8 o;
        #pragma unroll
        for (int j = 0; j < 8; j++) o[j] = f2bf(a0[j]);
        __builtin_nontemporal_store(o, (su16x8*)&out[(size_t)node * 256 + c0]);
    }
}

// ---------------- BN apply pass: Q = relu(BN(P)) * nsrc (sums 8 stats copies) ----------------
__global__ __launch_bounds__(256) void bnq_kernel(const ush* __restrict__ P,
                                                  const float* __restrict__ stats,
                                                  const float* __restrict__ gamma,
                                                  const float* __restrict__ beta,
                                                  const float* __restrict__ nsrc,
                                                  ush* __restrict__ Q)
{
    __shared__ float sa[HID], sb[HID];
    int tid = threadIdx.x;
    {
        float ssum = 0.f, qsum = 0.f;
        #pragma unroll
        for (int c8 = 0; c8 < 8; c8++) {
            ssum += stats[c8 * STATS_CPY + tid];
            qsum += stats[c8 * STATS_CPY + HID + tid];
        }
        const float inv_n = 1.f / (float)N_NODES;
        float mu = ssum * inv_n;
        float var = fmaf(-mu, mu, qsum * inv_n);
        float a = gamma[tid] * rsqrtf(var + BN_EPS);
        sa[tid] = a;
        sb[tid] = fmaf(-mu, a, beta[tid]);
    }
    __syncthreads();
    const int total = N_NODES * 32;
    for (int idx = blockIdx.x * 256 + tid; idx < total; idx += gridDim.x * 256) {
        int r = idx >> 5, c0 = (idx & 31) * 8;
        su16x8 v = __builtin_nontemporal_load((const su16x8*)&P[(size_t)r * HID + c0]);
        float ns = nsrc[r];
        su16x8 o;
        #pragma unroll
        for (int j = 0; j < 8; j++) {
            float x = fmaxf(fmaf(bf2f(v[j]), sa[c0 + j], sb[c0 + j]), 0.f) * ns;
            o[j] = f2bf(x);
        }
        *(su16x8*)&Q[(size_t)r * HID + c0] = o;
    }
}

// ---------------- per-graph max with fused BN+ReLU (hg pre-zeroed) ----------------
__global__ __launch_bounds__(256) void segmax_ab(const ush* __restrict__ pre,
                                                 const float* __restrict__ stats,
                                                 const float* __restrict__ gamma,
                                                 const float* __restrict__ beta,
                                                 const int* __restrict__ gstart,
                                                 float* __restrict__ hg) {
    int c = threadIdx.x;
    float ssum = 0.f, qsum = 0.f;
    #pragma unroll
    for (int c8 = 0; c8 < 8; c8++) {
        ssum += stats[c8 * STATS_CPY + c];
        qsum += stats[c8 * STATS_CPY + HID + c];
    }
    const float inv_n = 1.f / (float)N_NODES;
    float mu = ssum * inv_n;
    float var = fmaf(-mu, mu, qsum * inv_n);
    float a = gamma[c] * rsqrtf(var + BN_EPS);
    float b = fmaf(-mu, a, beta[c]);
    int g = blockIdx.x;
    int chunk = blockIdx.y;
    int beg = gstart[g], end = gstart[g + 1];
    int len = end - beg;
    int per = (len + 7) >> 3;
    int s = beg + chunk * per;
    int e = s + per; if (e > end) e = end;
    float m0 = 0.f, m1 = 0.f;
    int n = s;
    for (; n + 1 < e; n += 2) {
        m0 = fmaxf(m0, fmaf(bf2f(pre[(size_t)n * HID + c]), a, b));
        m1 = fmaxf(m1, fmaf(bf2f(pre[(size_t)(n + 1) * HID + c]), a, b));
    }
    if (n < e) m0 = fmaxf(m0, fmaf(bf2f(pre[(size_t)n * HID + c]), a, b));
    float m = fmaxf(fmaxf(m0, m1), 0.f);
    atomicMax((int*)&hg[g * HID + c], __float_as_int(m));
}

// ---------------- final fc ----------------
__global__ void fc_kernel(const float* __restrict__ hg, const float* __restrict__ w,
                          const float* __restrict__ b, float* __restrict__ out) {
    int idx = blockIdx.x * 256 + threadIdx.x;
    if (idx >= N_GRAPHS * OUT_DIM) return;
    int g = idx / OUT_DIM, j = idx % OUT_DIM;
    float s = b[j];
    for (int c = 0; c < HID; c++) s += hg[g * HID + c] * w[c * OUT_DIM + j];
    out[idx] = s;
}

extern "C" void kernel_launch(void* const* d_in, const int* in_sizes, int n_in,
                              void* d_out, int out_size, void* d_ws, size_t ws_size,
                              hipStream_t stream) {
    const float* h      = (const float*)d_in[0];
    const int*   src    = (const int*)d_in[1];
    const int*   dst    = (const int*)d_in[2];
    const int*   gids   = (const int*)d_in[3];
    const float* w_init = (const float*)d_in[4];
    const float* lw[3]    = { (const float*)d_in[5],  (const float*)d_in[9],  (const float*)d_in[13] };
    const float* lb[3]    = { (const float*)d_in[6],  (const float*)d_in[10], (const float*)d_in[14] };
    const float* gamma[3] = { (const float*)d_in[7],  (const float*)d_in[11], (const float*)d_in[15] };
    const float* beta[3]  = { (const float*)d_in[8],  (const float*)d_in[12], (const float*)d_in[16] };
    const float* fc_w = (const float*)d_in[17];
    const float* fc_b = (const float*)d_in[18];
    float* out = (float*)d_out;

    // ---- workspace layout ----
    char* ws = (char*)d_ws;
    size_t off_b = 0;
    auto alloc = [&](size_t bytes) { size_t o = off_b; off_b += (bytes + 255) & ~(size_t)255; return o; };
    size_t o_h0s   = alloc((size_t)N_NODES * NCLS * 2);
    size_t o_aggb  = alloc((size_t)N_NODES * HID * 2);
    size_t o_P     = alloc((size_t)N_NODES * HID * 2);
    size_t o_Q     = alloc((size_t)N_NODES * HID * 2);
    size_t o_wB0   = alloc((size_t)NCLS * FIN * 2);
    size_t o_lwT0  = alloc((size_t)HID * NCLS * 2);
    size_t o_lwT1  = alloc((size_t)HID * HID * 2);
    size_t o_lwT2  = alloc((size_t)HID * HID * 2);
    size_t o_nsrc  = alloc((size_t)N_NODES * 4);
    size_t o_ndst  = alloc((size_t)N_NODES * 4);
    size_t o_odeg8 = alloc((size_t)8 * N_NODES * 4);
    size_t o_roff  = alloc((size_t)(N_NODES + 1) * 4);
    size_t o_csr   = alloc((size_t)N_EDGES * 4);
    size_t o_stg   = alloc((size_t)N_EDGES * 4);
    size_t o_hist  = alloc((size_t)NBUCK * NBUCK * 4);
    size_t o_off   = alloc((size_t)NBUCK * NBUCK * 4);
    size_t o_bcnt  = alloc((size_t)(NBUCK + 1) * 4);
    size_t o_bbase = alloc((size_t)(NBUCK + 1) * 4);
    size_t o_stat8 = alloc((size_t)8 * STATS_CPY * 4);
    size_t o_gst   = alloc((size_t)(N_GRAPHS + 1) * 4);
    size_t o_hg    = alloc((size_t)N_GRAPHS * HID * 4);
    if (off_b > ws_size) return;

    ush*   h0s  = (ush*)(ws + o_h0s);
    ush*   aggb = (ush*)(ws + o_aggb);
    ush*   P    = (ush*)(ws + o_P);
    ush*   Q    = (ush*)(ws + o_Q);
    ush*   wB0  = (ush*)(ws + o_wB0);
    ush*   lwT[3] = { (ush*)(ws + o_lwT0), (ush*)(ws + o_lwT1), (ush*)(ws + o_lwT2) };
    float* nsrc = (float*)(ws + o_nsrc);
    float* ndst = (float*)(ws + o_ndst);
    int*   odeg8= (int*)(ws + o_odeg8);
    int*   roff = (int*)(ws + o_roff);
    int*   csr  = (int*)(ws + o_csr);
    unsigned int* stg = (unsigned int*)(ws + o_stg);
    int*   hist = (int*)(ws + o_hist);
    int*   boff = (int*)(ws + o_off);
    int*   bcnt = (int*)(ws + o_bcnt);
    int*   bbase= (int*)(ws + o_bbase);
    float* stats8 = (float*)(ws + o_stat8);
    int*   gst  = (int*)(ws + o_gst);
    float* hg   = (float*)(ws + o_hg);

    // zero accumulators
    zero_kernel<<<(8 * N_NODES + 255) / 256, 256, 0, stream>>>(odeg8, bcnt, stats8, hg);

    // edge pass 1: odeg + bucket histogram + bucket totals
    edge_pass1<<<NBUCK, 256, 0, stream>>>(src, dst, odeg8, hist, bcnt);

    // merged prep: nsrc + gstart + weight conversion
    misc_prep<<<(N_NODES + CVT_TOTAL + 255) / 256, 256, 0, stream>>>(
        odeg8, nsrc, gids, gst, w_init, lw[0], lw[1], lw[2], wB0, lwT[0], lwT[1], lwT[2]);

    // bucketed CSR build (XCD-local scatter)
    bscan_kernel<<<1, 512, 0, stream>>>(bcnt, bbase);
    boff_kernel<<<NBUCK, 512, 0, stream>>>(hist, bbase, boff);
    stage_kernel<<<NBUCK, 256, 0, stream>>>(src, dst, boff, stg);
    csr_kernel<<<NBUCK, 256, 0, stream>>>(stg, bbase, roff, ndst, csr);

    const int mblocks = (N_NODES + 127) / 128;
    const int aggblocks = (N_NODES * 64 + 255) / 256;

    // h0s = (h @ w_init^T) * nsrc   [N,128] bf16
    {
        dim3 grid(NCLS / 128, mblocks);
        mfma_gemm<true, false><<<grid, 256, 0, stream>>>(h, wB0, h0s, N_NODES, FIN, NCLS,
                                                         nsrc, nullptr, nullptr);
    }

    // ---- layer 0 ----
    agg128<<<aggblocks, 256, 0, stream>>>(h0s, roff, csr, aggb);
    {
        dim3 grid(HID / 128, mblocks);
        mfma_gemm<false, true><<<grid, 256, 0, stream>>>(aggb, lwT[0], P, N_NODES, NCLS, HID,
                                                         ndst, lb[0], stats8 + 0 * 2 * HID);
    }

    // ---- layers 1,2 ----
    for (int l = 1; l < 3; l++) {
        bnq_kernel<<<1024, 256, 0, stream>>>(P, stats8 + (l - 1) * 2 * HID,
                                             gamma[l - 1], beta[l - 1], nsrc, Q);
        agg256<<<aggblocks, 256, 0, stream>>>(Q, roff, csr, aggb);
        dim3 grid(HID / 128, mblocks);
        mfma_gemm<false, true><<<grid, 256, 0, stream>>>(aggb, lwT[l], P, N_NODES, HID, HID,
                                                         ndst, lb[l], stats8 + l * 2 * HID);
    }

    // ---- readout ----
    {
        dim3 grid(N_GRAPHS, 8);
        segmax_ab<<<grid, 256, 0, stream>>>(P, stats8 + 2 * 2 * HID, gamma[2], beta[2], gst, hg);
    }
    fc_kernel<<<(N_GRAPHS * OUT_DIM + 255) / 256, 256, 0, stream>>>(hg, fc_w, fc_b, out);
}

// Round 11
// 944.846 us; speedup vs baseline: 1.2534x; 1.1348x over previous
//
#include <hip/hip_runtime.h>
#include <hip/hip_bf16.h>

#define N_NODES 100000
#define N_EDGES 3200000
#define N_GRAPHS 128
#define FIN 512
#define NCLS 128
#define HID 256
#define OUT_DIM 10
#define BN_EPS 1e-5f

#define NBUCK 391                      // ceil(N_NODES/256): bucket = dst >> 8
#define EPB   ((N_EDGES + NBUCK - 1) / NBUCK)   // edges per partition block
#define STATS_CPY 1536                 // 3 layers * 2 * HID, per-XCD copy stride

typedef unsigned short ush;
typedef ush su16x8 __attribute__((ext_vector_type(8)));
typedef ush su16x4 __attribute__((ext_vector_type(4)));
typedef __bf16 bf16x8v __attribute__((ext_vector_type(8)));
typedef float f32x4v __attribute__((ext_vector_type(4)));

__device__ __forceinline__ float bf2f(ush u) {
    union { unsigned int i; float f; } v; v.i = ((unsigned int)u) << 16; return v.f;
}
// native conversion: compiler emits v_cvt_pk_bf16_f32 for pairs (RNE)
__device__ __forceinline__ ush f2bf(float f) {
    __hip_bfloat16 b = __float2bfloat16(f);
    return __builtin_bit_cast(ush, b);
}

// MFMA shim: works whether the gfx950 builtin takes 16-bit-int vectors or __bf16 vectors.
template <typename T>
__device__ __forceinline__ auto mfma_sel(T a, T b, f32x4v c, int)
    -> decltype(__builtin_amdgcn_mfma_f32_16x16x32_bf16(a, b, c, 0, 0, 0)) {
    return __builtin_amdgcn_mfma_f32_16x16x32_bf16(a, b, c, 0, 0, 0);
}
template <typename T>
__device__ __forceinline__ f32x4v mfma_sel(T a, T b, f32x4v c, long) {
    return __builtin_amdgcn_mfma_f32_16x16x32_bf16(
        __builtin_bit_cast(bf16x8v, a), __builtin_bit_cast(bf16x8v, b), c, 0, 0, 0);
}
__device__ __forceinline__ f32x4v MFMA_BF16(su16x8 a, su16x8 b, f32x4v c) {
    return mfma_sel(a, b, c, 0);
}

// ---------------- zero pass ----------------
__global__ void zero_kernel(int* __restrict__ odeg8, int* __restrict__ bcnt,
                            float* __restrict__ stats8, float* __restrict__ hg) {
    int i = blockIdx.x * 256 + threadIdx.x;
    if (i < 8 * N_NODES) odeg8[i] = 0;
    if (i <= NBUCK) bcnt[i] = 0;
    if (i < 8 * STATS_CPY) stats8[i] = 0.f;
    if (i < N_GRAPHS * HID) hg[i] = 0.f;
}

// ---------------- edge pass 1: out-degree (8 XCD-local copies) + bucket histogram + bcnt ----------------
__global__ __launch_bounds__(256) void edge_pass1(const int* __restrict__ src,
                                                  const int* __restrict__ dst,
                                                  int* __restrict__ odeg8,
                                                  int* __restrict__ hist,
                                                  int* __restrict__ bcnt) {
    __shared__ int hc[NBUCK];
    int tid = threadIdx.x, blk = blockIdx.x;
    for (int i = tid; i < NBUCK; i += 256) hc[i] = 0;
    __syncthreads();
    int e0 = blk * EPB, e1 = e0 + EPB; if (e1 > N_EDGES) e1 = N_EDGES;
    int c = blk & 7;
    for (int e = e0 + tid; e < e1; e += 256) {
        atomicAdd(&odeg8[(size_t)c * N_NODES + src[e]], 1);
        atomicAdd(&hc[dst[e] >> 8], 1);
    }
    __syncthreads();
    for (int i = tid; i < NBUCK; i += 256) {
        int v = hc[i];
        hist[(size_t)blk * NBUCK + i] = v;
        if (v) atomicAdd(&bcnt[i], v);
    }
}

// ---------------- merged prep: nsrc + gstart + weight conversion ----------------
#define CVT_TOTAL (NCLS * FIN + HID * NCLS + HID * HID + HID * HID)
__global__ void misc_prep(const int* __restrict__ odeg8, float* __restrict__ nsrc,
                          const int* __restrict__ gids, int* __restrict__ gstart,
                          const float* __restrict__ w0, const float* __restrict__ l0,
                          const float* __restrict__ l1, const float* __restrict__ l2,
                          ush* __restrict__ wB0, ush* __restrict__ t0,
                          ush* __restrict__ t1, ush* __restrict__ t2) {
    int i = blockIdx.x * 256 + threadIdx.x;
    if (i < N_NODES) {
        int od = 0;
        #pragma unroll
        for (int c = 0; c < 8; c++) od += odeg8[(size_t)c * N_NODES + i];
        nsrc[i] = od > 0 ? rsqrtf((float)od) : 0.f;
        int g = gids[i];
        int gp = (i == 0) ? -1 : gids[i - 1];
        for (int gg = gp + 1; gg <= g; gg++) gstart[gg] = i;
        if (i == N_NODES - 1) {
            for (int gg = g + 1; gg <= N_GRAPHS; gg++) gstart[gg] = N_NODES;
        }
        return;
    }
    i -= N_NODES;
    if (i < NCLS * FIN) { wB0[i] = f2bf(w0[i]); return; }
    i -= NCLS * FIN;
    if (i < HID * NCLS) { int n = i >> 7, k = i & 127; t0[i] = f2bf(l0[k * HID + n]); return; }
    i -= HID * NCLS;
    if (i < HID * HID) { int n = i >> 8, k = i & 255; t1[i] = f2bf(l1[k * HID + n]); return; }
    i -= HID * HID;
    if (i < HID * HID) { int n = i >> 8, k = i & 255; t2[i] = f2bf(l2[k * HID + n]); }
}

// ---------------- pass Bscan — exclusive scan of bucket totals ----------------
__global__ __launch_bounds__(512) void bscan_kernel(const int* __restrict__ bcnt,
                                                    int* __restrict__ bbase) {
    __shared__ int a[512];
    int tid = threadIdx.x;
    int v = (tid < NBUCK) ? bcnt[tid] : 0;
    a[tid] = v;
    __syncthreads();
    for (int s = 1; s < 512; s <<= 1) {
        int y = (tid >= s) ? a[tid - s] : 0;
        __syncthreads();
        a[tid] += y;
        __syncthreads();
    }
    if (tid < NBUCK) bbase[tid] = a[tid] - v;
    if (tid == 0) bbase[NBUCK] = N_EDGES;
}

// ---------------- pass B2 — per-(block,bucket) offsets ----------------
__global__ __launch_bounds__(512) void boff_kernel(const int* __restrict__ hist,
                                                   const int* __restrict__ bbase,
                                                   int* __restrict__ off) {
    __shared__ int a[512];
    int b = blockIdx.x, tid = threadIdx.x;
    int v = (tid < NBUCK) ? hist[(size_t)tid * NBUCK + b] : 0;
    a[tid] = v;
    __syncthreads();
    for (int s = 1; s < 512; s <<= 1) {
        int y = (tid >= s) ? a[tid - s] : 0;
        __syncthreads();
        a[tid] += y;
        __syncthreads();
    }
    if (tid < NBUCK) off[(size_t)tid * NBUCK + b] = bbase[b] + a[tid] - v;
}

// ---------------- pass C — stage edges into bucket-contiguous runs ----------------
__global__ __launch_bounds__(256) void stage_kernel(const int* __restrict__ src,
                                                    const int* __restrict__ dst,
                                                    const int* __restrict__ off,
                                                    unsigned int* __restrict__ staged) {
    __shared__ int cur[NBUCK];
    int tid = threadIdx.x, blk = blockIdx.x;
    for (int i = tid; i < NBUCK; i += 256) cur[i] = off[(size_t)blk * NBUCK + i];
    __syncthreads();
    int e0 = blk * EPB, e1 = e0 + EPB; if (e1 > N_EDGES) e1 = N_EDGES;
    for (int e = e0 + tid; e < e1; e += 256) {
        int d = dst[e], s = src[e];
        int pos = atomicAdd(&cur[d >> 8], 1);
        staged[pos] = ((unsigned int)(d & 255) << 24) | (unsigned int)s;
    }
}

// ---------------- pass D — exact CSR within bucket + roff + ndst ----------------
__global__ __launch_bounds__(256) void csr_kernel(const unsigned int* __restrict__ staged,
                                                  const int* __restrict__ bbase,
                                                  int* __restrict__ roff,
                                                  float* __restrict__ ndst,
                                                  int* __restrict__ csr) {
    __shared__ int cnt[256], pfx[256], cur[256];
    int b = blockIdx.x, tid = threadIdx.x;
    int beg = bbase[b], end = bbase[b + 1];
    int nodeBase = b * 256;
    int nNodes = N_NODES - nodeBase; if (nNodes > 256) nNodes = 256;
    cnt[tid] = 0;
    __syncthreads();
    for (int e = beg + tid; e < end; e += 256) atomicAdd(&cnt[staged[e] >> 24], 1);
    __syncthreads();
    int v = cnt[tid];
    pfx[tid] = v;
    __syncthreads();
    for (int s = 1; s < 256; s <<= 1) {
        int y = (tid >= s) ? pfx[tid - s] : 0;
        __syncthreads();
        pfx[tid] += y;
        __syncthreads();
    }
    int excl = pfx[tid] - v;
    pfx[tid] = excl;
    cur[tid] = 0;
    if (tid < nNodes) {
        int node = nodeBase + tid;
        roff[node] = beg + excl;
        ndst[node] = v > 0 ? rsqrtf((float)v) : 0.f;
    }
    if (b == NBUCK - 1 && tid == 0) roff[N_NODES] = N_EDGES;
    __syncthreads();
    for (int e = beg + tid; e < end; e += 256) {
        unsigned int w = staged[e];
        int dl = w >> 24;
        int pos = beg + pfx[dl] + atomicAdd(&cur[dl], 1);
        csr[pos] = (int)(w & 0xFFFFFFu);
    }
}

// ---------------- MFMA GEMM: C[M,NN](bf16) = A[M,K] @ BT[NN,K]^T ----------------
template <bool A_F32, bool DO_STATS>
__global__ __launch_bounds__(256) void mfma_gemm(
    const void* __restrict__ Aptr, const ush* __restrict__ BT,
    ush* __restrict__ C, int M, int K, int NN,
    const float* __restrict__ rowscale, const float* __restrict__ bias,
    float* __restrict__ stats)
{
    __shared__ __align__(16) ush As[128][40];
    __shared__ __align__(16) ush Bs[128][40];
    const int bn0 = blockIdx.x * 128;
    const int bm0 = blockIdx.y * 128;
    const int tid = threadIdx.x;
    const int lane = tid & 63;
    const int wv = tid >> 6;
    const int wm = (wv >> 1) * 64;
    const int wn = (wv & 1) * 64;
    const int lm = lane & 15;
    const int lg = lane >> 4;

    f32x4v zero = {0.f, 0.f, 0.f, 0.f};
    f32x4v acc[4][4];
    #pragma unroll
    for (int mi = 0; mi < 4; mi++)
        #pragma unroll
        for (int ni = 0; ni < 4; ni++) acc[mi][ni] = zero;

    for (int k0 = 0; k0 < K; k0 += 32) {
        #pragma unroll
        for (int i = 0; i < 2; i++) {
            int seg = tid + i * 256;
            int n = seg >> 2, kp = seg & 3;
            su16x8 v = *(const su16x8*)&BT[(size_t)(bn0 + n) * K + k0 + kp * 8];
            *(su16x8*)&Bs[n][kp * 8] = v;
        }
        if constexpr (A_F32) {
            const float* Af = (const float*)Aptr;
            #pragma unroll
            for (int i = 0; i < 4; i++) {
                int seg = tid + i * 256;
                int m = seg >> 3, kp = seg & 7;
                int gm = bm0 + m; if (gm >= M) gm = M - 1;
                float4 v = *(const float4*)&Af[(size_t)gm * K + k0 + kp * 4];
                su16x4 o = { f2bf(v.x), f2bf(v.y), f2bf(v.z), f2bf(v.w) };
                *(su16x4*)&As[m][kp * 4] = o;
            }
        } else {
            const ush* Ab = (const ush*)Aptr;
            #pragma unroll
            for (int i = 0; i < 2; i++) {
                int seg = tid + i * 256;
                int m = seg >> 2, kp = seg & 3;
                int gm = bm0 + m; if (gm >= M) gm = M - 1;
                su16x8 v = *(const su16x8*)&Ab[(size_t)gm * K + k0 + kp * 8];
                *(su16x8*)&As[m][kp * 8] = v;
            }
        }
        __syncthreads();
        su16x8 af[4], bfr[4];
        #pragma unroll
        for (int i = 0; i < 4; i++)
            af[i] = *(const su16x8*)&As[wm + i * 16 + lm][lg * 8];
        #pragma unroll
        for (int i = 0; i < 4; i++)
            bfr[i] = *(const su16x8*)&Bs[wn + i * 16 + lm][lg * 8];
        #pragma unroll
        for (int mi = 0; mi < 4; mi++)
            #pragma unroll
            for (int ni = 0; ni < 4; ni++)
                acc[mi][ni] = MFMA_BF16(af[mi], bfr[ni], acc[mi][ni]);
        __syncthreads();
    }

    float s4[4] = {0.f, 0.f, 0.f, 0.f}, q4[4] = {0.f, 0.f, 0.f, 0.f};
    #pragma unroll
    for (int mi = 0; mi < 4; mi++) {
        #pragma unroll
        for (int j = 0; j < 4; j++) {
            int gm = bm0 + wm + mi * 16 + lg * 4 + j;
            bool valid = gm < M;
            float rs = (rowscale && valid) ? rowscale[gm] : 1.f;
            #pragma unroll
            for (int ni = 0; ni < 4; ni++) {
                int gn = bn0 + wn + ni * 16 + lm;
                float v = acc[mi][ni][j] * rs;
                if (bias) v += bias[gn];
                if (valid) {
                    C[(size_t)gm * NN + gn] = f2bf(v);
                    if constexpr (DO_STATS) { s4[ni] += v; q4[ni] += v * v; }
                }
            }
        }
    }
    if constexpr (DO_STATS) {
        float* st = stats + ((blockIdx.x + gridDim.x * blockIdx.y) & 7) * STATS_CPY;
        #pragma unroll
        for (int ni = 0; ni < 4; ni++) {
            s4[ni] += __shfl_xor(s4[ni], 16); s4[ni] += __shfl_xor(s4[ni], 32);
            q4[ni] += __shfl_xor(q4[ni], 16); q4[ni] += __shfl_xor(q4[ni], 32);
        }
        if (lg == 0) {
            #pragma unroll
            for (int ni = 0; ni < 4; ni++) {
                int gn = bn0 + wn + ni * 16 + lm;
                atomicAdd(&st[gn], s4[ni]);
                atomicAdd(&st[HID + gn], q4[ni]);
            }
        }
    }
}

// ---------------- layer-0 aggregation (D=128): 4 contiguous slots/wave, unroll-4 (r6 body) ----------------
__global__ __launch_bounds__(256) void agg128(const ush* __restrict__ hs,
                                              const int* __restrict__ roff,
                                              const int* __restrict__ csr,
                                              ush* __restrict__ out)
{
    int node = (blockIdx.x * 256 + threadIdx.x) >> 6;
    int lane = threadIdx.x & 63;
    if (node >= N_NODES) return;
    int q = lane >> 4;
    int c0 = (lane & 15) * 8;
    int beg = roff[node], end = roff[node + 1];
    int len = end - beg;
    int s = beg + ((len * q) >> 2);
    int t = beg + ((len * (q + 1)) >> 2);
    float a0[8] = {}, a1[8] = {}, a2[8] = {}, a3[8] = {};
    int e = s;
    for (; e + 3 < t; e += 4) {
        int i0 = csr[e], i1 = csr[e + 1], i2 = csr[e + 2], i3 = csr[e + 3];
        su16x8 v0 = *(const su16x8*)&hs[(size_t)i0 * 128 + c0];
        su16x8 v1 = *(const su16x8*)&hs[(size_t)i1 * 128 + c0];
        su16x8 v2 = *(const su16x8*)&hs[(size_t)i2 * 128 + c0];
        su16x8 v3 = *(const su16x8*)&hs[(size_t)i3 * 128 + c0];
        #pragma unroll
        for (int j = 0; j < 8; j++) {
            a0[j] += bf2f(v0[j]); a1[j] += bf2f(v1[j]);
            a2[j] += bf2f(v2[j]); a3[j] += bf2f(v3[j]);
        }
    }
    for (; e < t; e++) {
        int i0 = csr[e];
        su16x8 v0 = *(const su16x8*)&hs[(size_t)i0 * 128 + c0];
        #pragma unroll
        for (int j = 0; j < 8; j++) a0[j] += bf2f(v0[j]);
    }
    #pragma unroll
    for (int j = 0; j < 8; j++) {
        a0[j] += a1[j] + a2[j] + a3[j];
        a0[j] += __shfl_xor(a0[j], 16);
        a0[j] += __shfl_xor(a0[j], 32);
    }
    if (lane < 16) {
        su16x8 o;
        #pragma unroll
        for (int j = 0; j < 8; j++) o[j] = f2bf(a0[j]);
        __builtin_nontemporal_store(o, (su16x8*)&out[(size_t)node * 128 + c0]);
    }
}

// ---------------- layers 1,2 aggregation over u8-quantized Q (r6 structure, half rows) ----------------
__global__ __launch_bounds__(256) void agg256_u8(const unsigned int* __restrict__ Qp,
                                                 const float* __restrict__ qs,
                                                 const int* __restrict__ roff,
                                                 const int* __restrict__ csr,
                                                 ush* __restrict__ out)
{
    int node = (blockIdx.x * 256 + threadIdx.x) >> 6;
    int lane = threadIdx.x & 63;
    if (node >= N_NODES) return;
    int half = lane >> 5;
    int cu = (lane & 31) * 2;       // u32 index within 64-u32 row
    int c0 = (lane & 31) * 8;       // output channel base
    int beg = roff[node], end = roff[node + 1];
    int len = end - beg;
    int s = beg + ((len * half) >> 1);
    int t = beg + ((len * (half + 1)) >> 1);
    float a0[8] = {}, a1[8] = {}, a2[8] = {}, a3[8] = {};
    int e = s;
    for (; e + 3 < t; e += 4) {
        int i0 = csr[e], i1 = csr[e + 1], i2 = csr[e + 2], i3 = csr[e + 3];
        float s0 = qs[i0], s1 = qs[i1], s2 = qs[i2], s3 = qs[i3];
        uint2 v0 = *(const uint2*)&Qp[(size_t)i0 * 64 + cu];
        uint2 v1 = *(const uint2*)&Qp[(size_t)i1 * 64 + cu];
        uint2 v2 = *(const uint2*)&Qp[(size_t)i2 * 64 + cu];
        uint2 v3 = *(const uint2*)&Qp[(size_t)i3 * 64 + cu];
        #pragma unroll
        for (int j = 0; j < 4; j++) {
            a0[j]     = fmaf((float)((v0.x >> (8 * j)) & 255u), s0, a0[j]);
            a0[4 + j] = fmaf((float)((v0.y >> (8 * j)) & 255u), s0, a0[4 + j]);
            a1[j]     = fmaf((float)((v1.x >> (8 * j)) & 255u), s1, a1[j]);
            a1[4 + j] = fmaf((float)((v1.y >> (8 * j)) & 255u), s1, a1[4 + j]);
            a2[j]     = fmaf((float)((v2.x >> (8 * j)) & 255u), s2, a2[j]);
            a2[4 + j] = fmaf((float)((v2.y >> (8 * j)) & 255u), s2, a2[4 + j]);
            a3[j]     = fmaf((float)((v3.x >> (8 * j)) & 255u), s3, a3[j]);
            a3[4 + j] = fmaf((float)((v3.y >> (8 * j)) & 255u), s3, a3[4 + j]);
        }
    }
    for (; e < t; e++) {
        int i0 = csr[e];
        float s0 = qs[i0];
        uint2 v0 = *(const uint2*)&Qp[(size_t)i0 * 64 + cu];
        #pragma unroll
        for (int j = 0; j < 4; j++) {
            a0[j]     = fmaf((float)((v0.x >> (8 * j)) & 255u), s0, a0[j]);
            a0[4 + j] = fmaf((float)((v0.y >> (8 * j)) & 255u), s0, a0[4 + j]);
        }
    }
    #pragma unroll
    for (int j = 0; j < 8; j++) {
        a0[j] += a1[j] + a2[j] + a3[j];
        a0[j] += __shfl_xor(a0[j], 32);
    }
    if (lane < 32) {
        su16x8 o;
        #pragma unroll
        for (int j = 0; j < 8; j++) o[j] = f2bf(a0[j]);
        __builtin_nontemporal_store(o, (su16x8*)&out[(size_t)node * 256 + c0]);
    }
}

// ---------------- BN apply + u8 quantize: Qp,qs <- relu(BN(P))*nsrc ----------------
__global__ __launch_bounds__(256) void bnq_u8(const ush* __restrict__ P,
                                              const float* __restrict__ stats,
                                              const float* __restrict__ gamma,
                                              const float* __restrict__ beta,
                                              const float* __restrict__ nsrc,
                                              unsigned int* __restrict__ Qp,
                                              float* __restrict__ qs)
{
    __shared__ float sa[HID], sb[HID];
    int tid = threadIdx.x;
    {
        float ssum = 0.f, qsum = 0.f;
        #pragma unroll
        for (int c8 = 0; c8 < 8; c8++) {
            ssum += stats[c8 * STATS_CPY + tid];
            qsum += stats[c8 * STATS_CPY + HID + tid];
        }
        const float inv_n = 1.f / (float)N_NODES;
        float mu = ssum * inv_n;
        float var = fmaf(-mu, mu, qsum * inv_n);
        float a = gamma[tid] * rsqrtf(var + BN_EPS);
        sa[tid] = a;
        sb[tid] = fmaf(-mu, a, beta[tid]);
    }
    __syncthreads();
    int lane = tid & 63;
    int c0 = lane * 4;
    int wid = (blockIdx.x * 256 + tid) >> 6;
    const int NW = (1024 * 256) >> 6;
    float ka0 = sa[c0], ka1 = sa[c0 + 1], ka2 = sa[c0 + 2], ka3 = sa[c0 + 3];
    float kb0 = sb[c0], kb1 = sb[c0 + 1], kb2 = sb[c0 + 2], kb3 = sb[c0 + 3];
    for (int r = wid; r < N_NODES; r += NW) {
        su16x4 v = *(const su16x4*)&P[(size_t)r * HID + c0];
        float ns = nsrc[r];
        float x0 = fmaxf(fmaf(bf2f(v[0]), ka0, kb0), 0.f) * ns;
        float x1 = fmaxf(fmaf(bf2f(v[1]), ka1, kb1), 0.f) * ns;
        float x2 = fmaxf(fmaf(bf2f(v[2]), ka2, kb2), 0.f) * ns;
        float x3 = fmaxf(fmaf(bf2f(v[3]), ka3, kb3), 0.f) * ns;
        float m = fmaxf(fmaxf(x0, x1), fmaxf(x2, x3));
        #pragma unroll
        for (int off = 1; off < 64; off <<= 1) m = fmaxf(m, __shfl_xor(m, off));
        float inv = m > 0.f ? 255.0f / m : 0.f;
        unsigned q0 = (unsigned)fminf(fmaf(x0, inv, 0.5f), 255.f);
        unsigned q1 = (unsigned)fminf(fmaf(x1, inv, 0.5f), 255.f);
        unsigned q2 = (unsigned)fminf(fmaf(x2, inv, 0.5f), 255.f);
        unsigned q3 = (unsigned)fminf(fmaf(x3, inv, 0.5f), 255.f);
        Qp[(size_t)r * 64 + lane] = q0 | (q1 << 8) | (q2 << 16) | (q3 << 24);
        if (lane == 0) qs[r] = m * (1.0f / 255.0f);
    }
}

// ---------------- per-graph max with fused BN+ReLU (hg pre-zeroed) ----------------
__global__ __launch_bounds__(256) void segmax_ab(const ush* __restrict__ pre,
                                                 const float* __restrict__ stats,
                                                 const float* __restrict__ gamma,
                                                 const float* __restrict__ beta,
                                                 const int* __restrict__ gstart,
                                                 float* __restrict__ hg) {
    int c = threadIdx.x;
    float ssum = 0.f, qsum = 0.f;
    #pragma unroll
    for (int c8 = 0; c8 < 8; c8++) {
        ssum += stats[c8 * STATS_CPY + c];
        qsum += stats[c8 * STATS_CPY + HID + c];
    }
    const float inv_n = 1.f / (float)N_NODES;
    float mu = ssum * inv_n;
    float var = fmaf(-mu, mu, qsum * inv_n);
    float a = gamma[c] * rsqrtf(var + BN_EPS);
    float b = fmaf(-mu, a, beta[c]);
    int g = blockIdx.x;
    int chunk = blockIdx.y;
    int beg = gstart[g], end = gstart[g + 1];
    int len = end - beg;
    int per = (len + 7) >> 3;
    int s = beg + chunk * per;
    int e = s + per; if (e > end) e = end;
    float m0 = 0.f, m1 = 0.f;
    int n = s;
    for (; n + 1 < e; n += 2) {
        m0 = fmaxf(m0, fmaf(bf2f(pre[(size_t)n * HID + c]), a, b));
        m1 = fmaxf(m1, fmaf(bf2f(pre[(size_t)(n + 1) * HID + c]), a, b));
    }
    if (n < e) m0 = fmaxf(m0, fmaf(bf2f(pre[(size_t)n * HID + c]), a, b));
    float m = fmaxf(fmaxf(m0, m1), 0.f);
    atomicMax((int*)&hg[g * HID + c], __float_as_int(m));
}

// ---------------- final fc ----------------
__global__ void fc_kernel(const float* __restrict__ hg, const float* __restrict__ w,
                          const float* __restrict__ b, float* __restrict__ out) {
    int idx = blockIdx.x * 256 + threadIdx.x;
    if (idx >= N_GRAPHS * OUT_DIM) return;
    int g = idx / OUT_DIM, j = idx % OUT_DIM;
    float s = b[j];
    for (int c = 0; c < HID; c++) s += hg[g * HID + c] * w[c * OUT_DIM + j];
    out[idx] = s;
}

extern "C" void kernel_launch(void* const* d_in, const int* in_sizes, int n_in,
                              void* d_out, int out_size, void* d_ws, size_t ws_size,
                              hipStream_t stream) {
    const float* h      = (const float*)d_in[0];
    const int*   src    = (const int*)d_in[1];
    const int*   dst    = (const int*)d_in[2];
    const int*   gids   = (const int*)d_in[3];
    const float* w_init = (const float*)d_in[4];
    const float* lw[3]    = { (const float*)d_in[5],  (const float*)d_in[9],  (const float*)d_in[13] };
    const float* lb[3]    = { (const float*)d_in[6],  (const float*)d_in[10], (const float*)d_in[14] };
    const float* gamma[3] = { (const float*)d_in[7],  (const float*)d_in[11], (const float*)d_in[15] };
    const float* beta[3]  = { (const float*)d_in[8],  (const float*)d_in[12], (const float*)d_in[16] };
    const float* fc_w = (const float*)d_in[17];
    const float* fc_b = (const float*)d_in[18];
    float* out = (float*)d_out;

    // ---- workspace layout ----
    char* ws = (char*)d_ws;
    size_t off_b = 0;
    auto alloc = [&](size_t bytes) { size_t o = off_b; off_b += (bytes + 255) & ~(size_t)255; return o; };
    size_t o_h0s   = alloc((size_t)N_NODES * NCLS * 2);
    size_t o_aggb  = alloc((size_t)N_NODES * HID * 2);
    size_t o_P     = alloc((size_t)N_NODES * HID * 2);
    size_t o_Qp    = alloc((size_t)N_NODES * 64 * 4);     // u8 rows as 64 u32 per row
    size_t o_qsc   = alloc((size_t)N_NODES * 4);
    size_t o_wB0   = alloc((size_t)NCLS * FIN * 2);
    size_t o_lwT0  = alloc((size_t)HID * NCLS * 2);
    size_t o_lwT1  = alloc((size_t)HID * HID * 2);
    size_t o_lwT2  = alloc((size_t)HID * HID * 2);
    size_t o_nsrc  = alloc((size_t)N_NODES * 4);
    size_t o_ndst  = alloc((size_t)N_NODES * 4);
    size_t o_odeg8 = alloc((size_t)8 * N_NODES * 4);
    size_t o_roff  = alloc((size_t)(N_NODES + 1) * 4);
    size_t o_csr   = alloc((size_t)N_EDGES * 4);
    size_t o_stg   = alloc((size_t)N_EDGES * 4);
    size_t o_hist  = alloc((size_t)NBUCK * NBUCK * 4);
    size_t o_off   = alloc((size_t)NBUCK * NBUCK * 4);
    size_t o_bcnt  = alloc((size_t)(NBUCK + 1) * 4);
    size_t o_bbase = alloc((size_t)(NBUCK + 1) * 4);
    size_t o_stat8 = alloc((size_t)8 * STATS_CPY * 4);
    size_t o_gst   = alloc((size_t)(N_GRAPHS + 1) * 4);
    size_t o_hg    = alloc((size_t)N_GRAPHS * HID * 4);
    if (off_b > ws_size) return;

    ush*   h0s  = (ush*)(ws + o_h0s);
    ush*   aggb = (ush*)(ws + o_aggb);
    ush*   P    = (ush*)(ws + o_P);
    unsigned int* Qp = (unsigned int*)(ws + o_Qp);
    float* qsc  = (float*)(ws + o_qsc);
    ush*   wB0  = (ush*)(ws + o_wB0);
    ush*   lwT[3] = { (ush*)(ws + o_lwT0), (ush*)(ws + o_lwT1), (ush*)(ws + o_lwT2) };
    float* nsrc = (float*)(ws + o_nsrc);
    float* ndst = (float*)(ws + o_ndst);
    int*   odeg8= (int*)(ws + o_odeg8);
    int*   roff = (int*)(ws + o_roff);
    int*   csr  = (int*)(ws + o_csr);
    unsigned int* stg = (unsigned int*)(ws + o_stg);
    int*   hist = (int*)(ws + o_hist);
    int*   boff = (int*)(ws + o_off);
    int*   bcnt = (int*)(ws + o_bcnt);
    int*   bbase= (int*)(ws + o_bbase);
    float* stats8 = (float*)(ws + o_stat8);
    int*   gst  = (int*)(ws + o_gst);
    float* hg   = (float*)(ws + o_hg);

    // zero accumulators
    zero_kernel<<<(8 * N_NODES + 255) / 256, 256, 0, stream>>>(odeg8, bcnt, stats8, hg);

    // edge pass 1: odeg + bucket histogram + bucket totals
    edge_pass1<<<NBUCK, 256, 0, stream>>>(src, dst, odeg8, hist, bcnt);

    // merged prep: nsrc + gstart + weight conversion
    misc_prep<<<(N_NODES + CVT_TOTAL + 255) / 256, 256, 0, stream>>>(
        odeg8, nsrc, gids, gst, w_init, lw[0], lw[1], lw[2], wB0, lwT[0], lwT[1], lwT[2]);

    // bucketed CSR build (XCD-local scatter)
    bscan_kernel<<<1, 512, 0, stream>>>(bcnt, bbase);
    boff_kernel<<<NBUCK, 512, 0, stream>>>(hist, bbase, boff);
    stage_kernel<<<NBUCK, 256, 0, stream>>>(src, dst, boff, stg);
    csr_kernel<<<NBUCK, 256, 0, stream>>>(stg, bbase, roff, ndst, csr);

    const int mblocks = (N_NODES + 127) / 128;
    const int aggblocks = (N_NODES * 64 + 255) / 256;

    // h0s = (h @ w_init^T) * nsrc   [N,128] bf16
    {
        dim3 grid(NCLS / 128, mblocks);
        mfma_gemm<true, false><<<grid, 256, 0, stream>>>(h, wB0, h0s, N_NODES, FIN, NCLS,
                                                         nsrc, nullptr, nullptr);
    }

    // ---- layer 0 ----
    agg128<<<aggblocks, 256, 0, stream>>>(h0s, roff, csr, aggb);
    {
        dim3 grid(HID / 128, mblocks);
        mfma_gemm<false, true><<<grid, 256, 0, stream>>>(aggb, lwT[0], P, N_NODES, NCLS, HID,
                                                         ndst, lb[0], stats8 + 0 * 2 * HID);
    }

    // ---- layers 1,2 ----
    for (int l = 1; l < 3; l++) {
        bnq_u8<<<1024, 256, 0, stream>>>(P, stats8 + (l - 1) * 2 * HID,
                                         gamma[l - 1], beta[l - 1], nsrc, Qp, qsc);
        agg256_u8<<<aggblocks, 256, 0, stream>>>(Qp, qsc, roff, csr, aggb);
        dim3 grid(HID / 128, mblocks);
        mfma_gemm<false, true><<<grid, 256, 0, stream>>>(aggb, lwT[l], P, N_NODES, HID, HID,
                                                         ndst, lb[l], stats8 + l * 2 * HID);
    }

    // ---- readout ----
    {
        dim3 grid(N_GRAPHS, 8);
        segmax_ab<<<grid, 256, 0, stream>>>(P, stats8 + 2 * 2 * HID, gamma[2], beta[2], gst, hg);
    }
    fc_kernel<<<(N_GRAPHS * OUT_DIM + 255) / 256, 256, 0, stream>>>(hg, fc_w, fc_b, out);
}